// Round 1
// baseline (913.880 us; speedup 1.0000x reference)
//
#include <hip/hip_runtime.h>
#include <math.h>

#define B_    8
#define N_    8192
#define M_    65536        // B_*N_
#define I_    512
#define E_    8
#define KF_   520          // I_+E_
#define D_    256
#define C_    10
#define NCLS_ 2

// ---------------- workspace layout (float offsets) ----------------
// X      : M_*512          x = relu([h|emb]@Wf+bf)
// PS     : 4*M_            partial s per N-col-block of gemm_ag
// S      : M_              gated attention scores
// STAT   : 256             max[80] at +0, 1/sumexp[80] at +80
// W      : M_              softmax weights per row
// CPART  : 8*32*10*512     per-(b,chunk) cluster partial sums
// CFEAT  : 80*512          pooled cluster features (pre-fc)
// CFEAT2 : 80*512          after intra fc + relu
// S2     : 128             inter-cluster scores
static const size_t X_OFF    = 0;
static const size_t PS_OFF   = X_OFF + (size_t)M_ * I_;
static const size_t S_OFF    = PS_OFF + 4 * (size_t)M_;
static const size_t STAT_OFF = S_OFF + (size_t)M_;
static const size_t W_OFF    = STAT_OFF + 256;
static const size_t CP_OFF   = W_OFF + (size_t)M_;
static const size_t CF_OFF   = CP_OFF + (size_t)B_ * 32 * C_ * I_;
static const size_t CF2_OFF  = CF_OFF + (size_t)B_ * C_ * I_;
static const size_t S2_OFF   = CF2_OFF + (size_t)B_ * C_ * I_;

__device__ __forceinline__ float sigf(float v) { return 1.0f / (1.0f + __expf(-v)); }

// =====================================================================
// K1: x = relu([h | emb[cid]] @ Wf + bf)       M=65536, K=520, N=512
// 128x128 block tile, BK=8, 256 threads, 8x8 micro-tile.
// Thread cols are split 4+4 (tx*4 and 64+tx*4) so B-frag ds_read_b128
// addresses stride 4 banks -> <=2-way aliasing (free).
// =====================================================================
__global__ __launch_bounds__(256) void gemm_x_kernel(
    const float* __restrict__ h, const int* __restrict__ cid,
    const float* __restrict__ emb, const float* __restrict__ Wf,
    const float* __restrict__ bfv, float* __restrict__ x)
{
    __shared__ float As[8][128];   // [k][m]
    __shared__ float Bs[8][128];   // [k][n]

    const int t   = threadIdx.x;
    const int bxn = blockIdx.x;           // 0..3   (N col block)
    const int m0  = blockIdx.y * 128;     // row block
    const int n0  = bxn * 128;
    const int tx  = t & 15, ty = t >> 4;

    const int ar = t >> 1;                // 0..127 staged row
    const int ak = (t & 1) * 4;           // 0 or 4
    const int bk = t >> 5;                // 0..7
    const int bn = (t & 31) * 4;          // 0..124

    float acc[8][8];
#pragma unroll
    for (int i = 0; i < 8; ++i)
#pragma unroll
        for (int j = 0; j < 8; ++j) acc[i][j] = 0.0f;

    for (int k0 = 0; k0 < KF_; k0 += 8) {
        float4 av;
        if (k0 < 512) {
            av = *(const float4*)(&h[(size_t)(m0 + ar) * 512 + k0 + ak]);
        } else {                           // last tile: embedding columns
            int c = cid[m0 + ar];
            av = *(const float4*)(&emb[c * 8 + ak]);
        }
        float4 bv = *(const float4*)(&Wf[(size_t)(k0 + bk) * 512 + n0 + bn]);

        __syncthreads();
        As[ak + 0][ar] = av.x; As[ak + 1][ar] = av.y;
        As[ak + 2][ar] = av.z; As[ak + 3][ar] = av.w;
        *(float4*)(&Bs[bk][bn]) = bv;
        __syncthreads();

#pragma unroll
        for (int kk = 0; kk < 8; ++kk) {
            float af[8], bfr[8];
            *(float4*)(af)      = *(const float4*)(&As[kk][ty * 8]);
            *(float4*)(af + 4)  = *(const float4*)(&As[kk][ty * 8 + 4]);
            *(float4*)(bfr)     = *(const float4*)(&Bs[kk][tx * 4]);
            *(float4*)(bfr + 4) = *(const float4*)(&Bs[kk][64 + tx * 4]);
#pragma unroll
            for (int i = 0; i < 8; ++i)
#pragma unroll
                for (int j = 0; j < 8; ++j) acc[i][j] += af[i] * bfr[j];
        }
    }

    float4 b0 = *(const float4*)(&bfv[n0 + tx * 4]);
    float4 b1 = *(const float4*)(&bfv[n0 + 64 + tx * 4]);
#pragma unroll
    for (int i = 0; i < 8; ++i) {
        int row = m0 + ty * 8 + i;
        float4 o0, o1;
        o0.x = fmaxf(acc[i][0] + b0.x, 0.f); o0.y = fmaxf(acc[i][1] + b0.y, 0.f);
        o0.z = fmaxf(acc[i][2] + b0.z, 0.f); o0.w = fmaxf(acc[i][3] + b0.w, 0.f);
        o1.x = fmaxf(acc[i][4] + b1.x, 0.f); o1.y = fmaxf(acc[i][5] + b1.y, 0.f);
        o1.z = fmaxf(acc[i][6] + b1.z, 0.f); o1.w = fmaxf(acc[i][7] + b1.w, 0.f);
        *(float4*)(&x[(size_t)row * 512 + n0 + tx * 4])      = o0;
        *(float4*)(&x[(size_t)row * 512 + n0 + 64 + tx * 4]) = o1;
    }
}

// =====================================================================
// K2: gated attention scores.  B matrix is Wa/Wb column-interleaved:
// global col G -> d=G>>1, (G&1)? Wb : Wa.  Each thread's 8 cols = 4 (a,g)
// pairs, epilogue computes sum_d tanh(a)*sig(g)*Wc[d] partial per row,
// reduced over tx into ps[colblock][m].
// =====================================================================
__global__ __launch_bounds__(256) void gemm_ag_kernel(
    const float* __restrict__ x,
    const float* __restrict__ Wa, const float* __restrict__ bav,
    const float* __restrict__ Wb, const float* __restrict__ bbv,
    const float* __restrict__ Wc, float* __restrict__ ps)
{
    __shared__ float As[8][128];
    __shared__ float Bs[8][128];
    __shared__ float red[128][17];   // +1 pad to break write conflicts

    const int t   = threadIdx.x;
    const int bxn = blockIdx.x;           // 0..3
    const int m0  = blockIdx.y * 128;
    const int tx  = t & 15, ty = t >> 4;

    const int ar = t >> 1;
    const int ak = (t & 1) * 4;
    const int bk = t >> 5;                // 0..7
    const int bn = (t & 31) * 4;          // 0..124

    float acc[8][8];
#pragma unroll
    for (int i = 0; i < 8; ++i)
#pragma unroll
        for (int j = 0; j < 8; ++j) acc[i][j] = 0.0f;

    const int dstage = bxn * 64 + (t & 31) * 2;   // d for staged pair

    for (int k0 = 0; k0 < 512; k0 += 8) {
        float4 av = *(const float4*)(&x[(size_t)(m0 + ar) * 512 + k0 + ak]);
        float2 a2 = *(const float2*)(&Wa[(size_t)(k0 + bk) * 256 + dstage]);
        float2 g2 = *(const float2*)(&Wb[(size_t)(k0 + bk) * 256 + dstage]);

        __syncthreads();
        As[ak + 0][ar] = av.x; As[ak + 1][ar] = av.y;
        As[ak + 2][ar] = av.z; As[ak + 3][ar] = av.w;
        float4 bi; bi.x = a2.x; bi.y = g2.x; bi.z = a2.y; bi.w = g2.y;
        *(float4*)(&Bs[bk][bn]) = bi;
        __syncthreads();

#pragma unroll
        for (int kk = 0; kk < 8; ++kk) {
            float af[8], bfr[8];
            *(float4*)(af)      = *(const float4*)(&As[kk][ty * 8]);
            *(float4*)(af + 4)  = *(const float4*)(&As[kk][ty * 8 + 4]);
            *(float4*)(bfr)     = *(const float4*)(&Bs[kk][tx * 4]);
            *(float4*)(bfr + 4) = *(const float4*)(&Bs[kk][64 + tx * 4]);
#pragma unroll
            for (int i = 0; i < 8; ++i)
#pragma unroll
                for (int j = 0; j < 8; ++j) acc[i][j] += af[i] * bfr[j];
        }
    }

    // epilogue: this thread's pairs are d0,d0+1,d0+32,d0+33
    const int d0 = bxn * 64 + tx * 2;
    const int d2 = d0 + 32;
    float ba0 = bav[d0], ba1 = bav[d0 + 1], ba2 = bav[d2], ba3 = bav[d2 + 1];
    float bb0 = bbv[d0], bb1 = bbv[d0 + 1], bb2 = bbv[d2], bb3 = bbv[d2 + 1];
    float w0 = Wc[d0], w1 = Wc[d0 + 1], w2 = Wc[d2], w3 = Wc[d2 + 1];

#pragma unroll
    for (int i = 0; i < 8; ++i) {
        float p = tanhf(acc[i][0] + ba0) * sigf(acc[i][1] + bb0) * w0
                + tanhf(acc[i][2] + ba1) * sigf(acc[i][3] + bb1) * w1
                + tanhf(acc[i][4] + ba2) * sigf(acc[i][5] + bb2) * w2
                + tanhf(acc[i][6] + ba3) * sigf(acc[i][7] + bb3) * w3;
        red[ty * 8 + i][tx] = p;
    }
    __syncthreads();
    if (t < 128) {
        float s = 0.f;
#pragma unroll
        for (int j = 0; j < 16; ++j) s += red[t][j];
        ps[(size_t)bxn * M_ + m0 + t] = s;
    }
}

// K3: s[m] = sum of 4 column-block partials + bc
__global__ void s_combine_kernel(const float* __restrict__ ps,
                                 const float* __restrict__ bc,
                                 float* __restrict__ s)
{
    int m = blockIdx.x * 256 + threadIdx.x;
    s[m] = ps[m] + ps[M_ + m] + ps[2 * (size_t)M_ + m] + ps[3 * (size_t)M_ + m] + bc[0];
}

// K4: per-(b,c) segment max and 1/sumexp
__global__ __launch_bounds__(256) void stats_kernel(
    const float* __restrict__ s, const int* __restrict__ cid,
    float* __restrict__ stat)
{
    __shared__ float red[256];
    const int b = blockIdx.x / C_;
    const int c = blockIdx.x % C_;
    const int t = threadIdx.x;

    float mx = -3.0e38f;
    for (int n = t; n < N_; n += 256)
        if (cid[b * N_ + n] == c) mx = fmaxf(mx, s[b * N_ + n]);
    red[t] = mx; __syncthreads();
    for (int off = 128; off > 0; off >>= 1) {
        if (t < off) red[t] = fmaxf(red[t], red[t + off]);
        __syncthreads();
    }
    mx = red[0]; __syncthreads();

    float sum = 0.f;
    for (int n = t; n < N_; n += 256)
        if (cid[b * N_ + n] == c) sum += expf(s[b * N_ + n] - mx);
    red[t] = sum; __syncthreads();
    for (int off = 128; off > 0; off >>= 1) {
        if (t < off) red[t] += red[t + off];
        __syncthreads();
    }
    if (t == 0) {
        stat[blockIdx.x]      = mx;
        stat[80 + blockIdx.x] = 1.0f / red[0];
    }
}

// K5a: per-row softmax weight
__global__ void weight_kernel(const float* __restrict__ s, const int* __restrict__ cid,
                              const float* __restrict__ stat, float* __restrict__ w)
{
    int m = blockIdx.x * 256 + threadIdx.x;
    int b = m >> 13;               // /N_
    int c = cid[m];
    w[m] = expf(s[m] - stat[b * C_ + c]) * stat[80 + b * C_ + c];
}

// K5b: segmented weighted sums into per-chunk partials (deterministic, no atomics)
__global__ __launch_bounds__(256) void cpart_kernel(
    const float* __restrict__ x, const int* __restrict__ cid,
    const float* __restrict__ w, float* __restrict__ cpart)
{
    __shared__ float acc[C_][512];
    const int b     = blockIdx.x >> 5;
    const int chunk = blockIdx.x & 31;
    const int t     = threadIdx.x;

#pragma unroll
    for (int c = 0; c < C_; ++c) { acc[c][t] = 0.f; acc[c][t + 256] = 0.f; }
    __syncthreads();

    const int base = b * N_ + chunk * 256;
    for (int r = 0; r < 256; ++r) {
        int m = base + r;
        int c = cid[m];
        float wv = w[m];
        acc[c][t]       += wv * x[(size_t)m * 512 + t];
        acc[c][t + 256] += wv * x[(size_t)m * 512 + 256 + t];
    }
    __syncthreads();
#pragma unroll
    for (int c = 0; c < C_; ++c) {
        size_t o = (((size_t)blockIdx.x) * C_ + c) * 512;
        cpart[o + t]       = acc[c][t];
        cpart[o + 256 + t] = acc[c][t + 256];
    }
}

// K6a: reduce 32 chunks -> cfeat[b,c,i]
__global__ void creduce_kernel(const float* __restrict__ cpart, float* __restrict__ cfeat)
{
    int o = blockIdx.x * 256 + threadIdx.x;   // < 80*512
    int i = o & 511;
    int bc = o >> 9;                           // b*10+c
    int b = bc / C_, c = bc % C_;
    float sum = 0.f;
    for (int ch = 0; ch < 32; ++ch)
        sum += cpart[(((size_t)(b * 32 + ch)) * C_ + c) * 512 + i];
    cfeat[o] = sum;
}

// K6b: cfeat2 = relu(cfeat @ Wfc + bfc)   (80 rows)
__global__ __launch_bounds__(256) void intra_fc_kernel(
    const float* __restrict__ cfeat, const float* __restrict__ Wfc,
    const float* __restrict__ bfc, float* __restrict__ cfeat2)
{
    __shared__ float row[512];
    const int bc = blockIdx.x;
    const int t  = threadIdx.x;
    row[t] = cfeat[bc * 512 + t]; row[t + 256] = cfeat[bc * 512 + 256 + t];
    __syncthreads();
    float a0 = 0.f, a1 = 0.f;
    for (int i = 0; i < 512; ++i) {
        float rv = row[i];
        a0 += rv * Wfc[(size_t)i * 512 + t];
        a1 += rv * Wfc[(size_t)i * 512 + 256 + t];
    }
    cfeat2[bc * 512 + t]       = fmaxf(a0 + bfc[t], 0.f);
    cfeat2[bc * 512 + 256 + t] = fmaxf(a1 + bfc[256 + t], 0.f);
}

// K7: inter-cluster gated attention scores s2[b,c]
__global__ __launch_bounds__(256) void inter_score_kernel(
    const float* __restrict__ cfeat2,
    const float* __restrict__ Wa2, const float* __restrict__ ba2,
    const float* __restrict__ Wb2, const float* __restrict__ bb2,
    const float* __restrict__ Wc2, const float* __restrict__ bc2,
    float* __restrict__ s2)
{
    __shared__ float row[512];
    __shared__ float red[256];
    const int bc = blockIdx.x;
    const int t  = threadIdx.x;
    row[t] = cfeat2[bc * 512 + t]; row[t + 256] = cfeat2[bc * 512 + 256 + t];
    __syncthreads();
    float pa = 0.f, pg = 0.f;
    for (int f = 0; f < 512; ++f) {
        float rv = row[f];
        pa += rv * Wa2[(size_t)f * 256 + t];
        pg += rv * Wb2[(size_t)f * 256 + t];
    }
    float v = tanhf(pa + ba2[t]) * sigf(pg + bb2[t]) * Wc2[t];
    red[t] = v; __syncthreads();
    for (int off = 128; off > 0; off >>= 1) {
        if (t < off) red[t] += red[t + off];
        __syncthreads();
    }
    if (t == 0) s2[bc] = red[0] + bc2[0];
}

// K8: softmax over C, slide pooling, final fc + classifier
__global__ __launch_bounds__(256) void final_kernel(
    const float* __restrict__ cfeat2, const float* __restrict__ s2,
    const float* __restrict__ Wfc2, const float* __restrict__ bfc2,
    const float* __restrict__ Wcls, const float* __restrict__ bcls,
    float* __restrict__ out)
{
    __shared__ float A2[C_];
    __shared__ float slide[512];
    __shared__ float slide2[256];
    const int b = blockIdx.x;
    const int t = threadIdx.x;

    if (t < C_) A2[t] = s2[b * C_ + t];
    __syncthreads();
    float mx = -3.0e38f;
    for (int c = 0; c < C_; ++c) mx = fmaxf(mx, A2[c]);
    float sum = 0.f;
    for (int c = 0; c < C_; ++c) sum += expf(A2[c] - mx);
    __syncthreads();
    if (t < C_) A2[t] = expf(A2[t] - mx) / sum;
    __syncthreads();

    float s0 = 0.f, s1 = 0.f;
    for (int c = 0; c < C_; ++c) {
        float a = A2[c];
        s0 += a * cfeat2[(b * C_ + c) * 512 + t];
        s1 += a * cfeat2[(b * C_ + c) * 512 + 256 + t];
    }
    slide[t] = s0; slide[t + 256] = s1;
    __syncthreads();

    float acc = 0.f;
    for (int f = 0; f < 512; ++f) acc += slide[f] * Wfc2[(size_t)f * 256 + t];
    slide2[t] = fmaxf(acc + bfc2[t], 0.f);
    __syncthreads();

    if (t < NCLS_) {
        float l = bcls[t];
        for (int o = 0; o < 256; ++o) l += slide2[o] * Wcls[o * 2 + t];
        out[b * 2 + t] = l;
    }
}

extern "C" void kernel_launch(void* const* d_in, const int* in_sizes, int n_in,
                              void* d_out, int out_size, void* d_ws, size_t ws_size,
                              hipStream_t stream)
{
    (void)in_sizes; (void)n_in; (void)out_size; (void)ws_size;
    const float* h    = (const float*)d_in[0];
    const int*   cid  = (const int*)  d_in[1];
    const float* emb  = (const float*)d_in[2];
    const float* Wf   = (const float*)d_in[3];
    const float* bf   = (const float*)d_in[4];
    const float* Wa   = (const float*)d_in[5];
    const float* ba   = (const float*)d_in[6];
    const float* Wb   = (const float*)d_in[7];
    const float* bb   = (const float*)d_in[8];
    const float* Wc   = (const float*)d_in[9];
    const float* bc   = (const float*)d_in[10];
    const float* Wfc  = (const float*)d_in[11];
    const float* bfc  = (const float*)d_in[12];
    const float* Wa2  = (const float*)d_in[13];
    const float* ba2  = (const float*)d_in[14];
    const float* Wb2  = (const float*)d_in[15];
    const float* bb2  = (const float*)d_in[16];
    const float* Wc2  = (const float*)d_in[17];
    const float* bc2  = (const float*)d_in[18];
    const float* Wfc2 = (const float*)d_in[19];
    const float* bfc2 = (const float*)d_in[20];
    const float* Wcls = (const float*)d_in[21];
    const float* bcls = (const float*)d_in[22];

    float* ws     = (float*)d_ws;
    float* X      = ws + X_OFF;
    float* PS     = ws + PS_OFF;
    float* S      = ws + S_OFF;
    float* STAT   = ws + STAT_OFF;
    float* W      = ws + W_OFF;
    float* CPART  = ws + CP_OFF;
    float* CFEAT  = ws + CF_OFF;
    float* CFEAT2 = ws + CF2_OFF;
    float* S2     = ws + S2_OFF;
    float* out    = (float*)d_out;

    gemm_x_kernel<<<dim3(4, 512), 256, 0, stream>>>(h, cid, emb, Wf, bf, X);
    gemm_ag_kernel<<<dim3(4, 512), 256, 0, stream>>>(X, Wa, ba, Wb, bb, Wc, PS);
    s_combine_kernel<<<256, 256, 0, stream>>>(PS, bc, S);
    stats_kernel<<<B_ * C_, 256, 0, stream>>>(S, cid, STAT);
    weight_kernel<<<256, 256, 0, stream>>>(S, cid, STAT, W);
    cpart_kernel<<<B_ * 32, 256, 0, stream>>>(X, cid, W, CPART);
    creduce_kernel<<<160, 256, 0, stream>>>(CPART, CFEAT);
    intra_fc_kernel<<<B_ * C_, 256, 0, stream>>>(CFEAT, Wfc, bfc, CFEAT2);
    inter_score_kernel<<<B_ * C_, 256, 0, stream>>>(CFEAT2, Wa2, ba2, Wb2, bb2, Wc2, bc2, S2);
    final_kernel<<<B_, 256, 0, stream>>>(CFEAT2, S2, Wfc2, bfc2, Wcls, bcls, out);
}

// Round 2
// 357.031 us; speedup vs baseline: 2.5597x; 2.5597x over previous
//
#include <hip/hip_runtime.h>
#include <math.h>

#define B_    8
#define N_    8192
#define M_    65536        // B_*N_
#define I_    512
#define E_    8
#define D_    256
#define C_    10
#define NCLS_ 2

typedef unsigned short ushort_t;
typedef ushort_t ushortx8 __attribute__((ext_vector_type(8)));
typedef __bf16   bf16x8  __attribute__((ext_vector_type(8)));
typedef float    f32x4   __attribute__((ext_vector_type(4)));

// ---------------- workspace layout (byte offsets) ----------------
// XB   : bf16 x [M_,512]                      67108864
// HB   : bf16 h [M_,512]  (dead after gemm_x) 67108864
//   overlap zone inside HB (used after gemm_x):
//   PS, S, STAT, W, CPART, CFEAT, CFEAT2, S2  (~8.2 MB)
// WFT  : bf16 WfT [512 n][512 k]               524288
// BAG  : bf16 BagT [512 c][512 k]              524288
// EMBW : f32 [10][512]                          20480
static const size_t XB_OFF   = 0;
static const size_t HB_OFF   = 67108864;
static const size_t WFT_OFF  = 134217728;
static const size_t BAG_OFF  = WFT_OFF + 524288;
static const size_t EMBW_OFF = BAG_OFF + 524288;
// overlap zone (inside HB, live only after gemm_x completes)
static const size_t PS_OFF   = HB_OFF;                    // 8*M_*4 = 2097152
static const size_t S_OFF    = PS_OFF + 2097152;          // M_*4
static const size_t STAT_OFF = S_OFF + 262144;            // 1024
static const size_t W_OFF    = STAT_OFF + 1024;           // M_*4
static const size_t CP_OFF   = W_OFF + 262144;            // 8*32*10*512*4
static const size_t CF_OFF   = CP_OFF + 5242880;          // 80*512*4
static const size_t CF2_OFF  = CF_OFF + 163840;
static const size_t S2_OFF   = CF2_OFF + 163840;

__device__ __forceinline__ float sigf(float v) { return 1.0f / (1.0f + __expf(-v)); }

__device__ __forceinline__ ushort_t f2bf(float f) {
    union { float f; unsigned u; } v; v.f = f;
    unsigned r = v.u + 0x7FFF + ((v.u >> 16) & 1);   // RNE (finite data)
    return (ushort_t)(r >> 16);
}
__device__ __forceinline__ float bf2f(ushort_t u) {
    union { unsigned u; float f; } v; v.u = ((unsigned)u) << 16; return v.f;
}

// =====================================================================
// P1: convert h f32 -> bf16 (8 elems / thread)
// =====================================================================
__global__ __launch_bounds__(256) void conv_h_kernel(
    const float* __restrict__ h, ushort_t* __restrict__ hb)
{
    size_t i = (size_t)blockIdx.x * 256 + threadIdx.x;   // ushortx8 index
    const float4* h4 = (const float4*)h;
    float4 v0 = h4[i * 2], v1 = h4[i * 2 + 1];
    ushortx8 o;
    o[0] = f2bf(v0.x); o[1] = f2bf(v0.y); o[2] = f2bf(v0.z); o[3] = f2bf(v0.w);
    o[4] = f2bf(v1.x); o[5] = f2bf(v1.y); o[6] = f2bf(v1.z); o[7] = f2bf(v1.w);
    *(ushortx8*)(hb + i * 8) = o;
}

// P2: WfT[n][k] = bf16(Wf[k][n])   (512x512, k<512 slice)
__global__ __launch_bounds__(256) void prep_wft_kernel(
    const float* __restrict__ Wf, ushort_t* __restrict__ wft)
{
    int idx = blockIdx.x * 256 + threadIdx.x;    // 0..262143
    int n = idx >> 9, k = idx & 511;
    wft[(size_t)n * 512 + k] = f2bf(Wf[(size_t)k * 512 + n]);
}

// P3: BagT[c][k]: col c -> blk=c>>6, w=c&63, d=blk*32+(w&31); a if w<32 else g
__global__ __launch_bounds__(256) void prep_bag_kernel(
    const float* __restrict__ Wa, const float* __restrict__ Wb,
    ushort_t* __restrict__ bag)
{
    int idx = blockIdx.x * 256 + threadIdx.x;
    int c = idx >> 9, k = idx & 511;
    int blk = c >> 6, w = c & 63, d = blk * 32 + (w & 31);
    float v = (w < 32) ? Wa[(size_t)k * 256 + d] : Wb[(size_t)k * 256 + d];
    bag[(size_t)c * 512 + k] = f2bf(v);
}

// P4: embW[c][n] = bf[n] + sum_e emb[c][e]*Wf[512+e][n]   (f32, 10x512)
__global__ __launch_bounds__(256) void prep_embw_kernel(
    const float* __restrict__ emb, const float* __restrict__ Wf,
    const float* __restrict__ bfv, float* __restrict__ embW)
{
    int idx = blockIdx.x * 256 + threadIdx.x;    // < 5120
    int c = idx >> 9, n = idx & 511;
    float s = bfv[n];
#pragma unroll
    for (int e = 0; e < 8; ++e) s += emb[c * 8 + e] * Wf[(size_t)(512 + e) * 512 + n];
    embW[(size_t)c * 512 + n] = s;
}

// =====================================================================
// K1: x = relu(h@Wf[:512] + embW[cid])  -> bf16   MFMA 128x128 tile
// 256 thr = 4 waves (2x2), wave tile 64x64, BK=32, 16x16x32 bf16 MFMA.
// LDS [row][4 chunks of 16B] with chunk ^= (row>>1)&3 swizzle.
// =====================================================================
__global__ __launch_bounds__(256) void gemm_x_mfma(
    const ushort_t* __restrict__ hb, const int* __restrict__ cid,
    const ushort_t* __restrict__ wft, const float* __restrict__ embW,
    ushort_t* __restrict__ xb)
{
    __shared__ ushort_t As[128 * 32];
    __shared__ ushort_t Bs[128 * 32];

    const int t  = threadIdx.x;
    const int n0 = blockIdx.x * 128;
    const int m0 = blockIdx.y * 128;
    const int wid = t >> 6, wr = wid >> 1, wc = wid & 1;
    const int l  = t & 63, lr = l & 15, lg = l >> 4;

    const int r0 = t >> 2, ch = t & 3;
    const int swz = ((ch ^ ((r0 >> 1) & 3)) << 4);   // same for row r0 and 64+r0

    f32x4 acc[4][4] = {};

    const size_t aoff0 = ((size_t)(m0 + r0) * 512) + ch * 8;
    const size_t aoff1 = ((size_t)(m0 + 64 + r0) * 512) + ch * 8;
    const size_t boff0 = ((size_t)(n0 + r0) * 512) + ch * 8;
    const size_t boff1 = ((size_t)(n0 + 64 + r0) * 512) + ch * 8;

    ushortx8 sa0 = *(const ushortx8*)(hb + aoff0);
    ushortx8 sa1 = *(const ushortx8*)(hb + aoff1);
    ushortx8 sb0 = *(const ushortx8*)(wft + boff0);
    ushortx8 sb1 = *(const ushortx8*)(wft + boff1);

    for (int kt = 0; kt < 16; ++kt) {
        __syncthreads();
        *(ushortx8*)((char*)As + r0 * 64 + swz)        = sa0;
        *(ushortx8*)((char*)As + (64 + r0) * 64 + swz) = sa1;
        *(ushortx8*)((char*)Bs + r0 * 64 + swz)        = sb0;
        *(ushortx8*)((char*)Bs + (64 + r0) * 64 + swz) = sb1;
        __syncthreads();
        if (kt < 15) {
            int k = (kt + 1) * 32;
            sa0 = *(const ushortx8*)(hb + aoff0 + k);
            sa1 = *(const ushortx8*)(hb + aoff1 + k);
            sb0 = *(const ushortx8*)(wft + boff0 + k);
            sb1 = *(const ushortx8*)(wft + boff1 + k);
        }
        bf16x8 af[4], bg[4];
#pragma unroll
        for (int mi = 0; mi < 4; ++mi) {
            int R = wr * 64 + mi * 16 + lr;
            af[mi] = *(const bf16x8*)((const char*)As + R * 64 + ((lg ^ ((R >> 1) & 3)) << 4));
        }
#pragma unroll
        for (int ni = 0; ni < 4; ++ni) {
            int Cc = wc * 64 + ni * 16 + lr;
            bg[ni] = *(const bf16x8*)((const char*)Bs + Cc * 64 + ((lg ^ ((Cc >> 1) & 3)) << 4));
        }
#pragma unroll
        for (int mi = 0; mi < 4; ++mi)
#pragma unroll
            for (int ni = 0; ni < 4; ++ni)
                acc[mi][ni] = __builtin_amdgcn_mfma_f32_16x16x32_bf16(af[mi], bg[ni], acc[mi][ni], 0, 0, 0);
    }

    // epilogue: + embW[cid[row]][col], relu, bf16 store
#pragma unroll
    for (int mi = 0; mi < 4; ++mi) {
#pragma unroll
        for (int r = 0; r < 4; ++r) {
            int row = m0 + wr * 64 + mi * 16 + lg * 4 + r;
            const float* ew = embW + (size_t)cid[row] * 512;
#pragma unroll
            for (int ni = 0; ni < 4; ++ni) {
                int col = n0 + wc * 64 + ni * 16 + lr;
                float v = acc[mi][ni][r] + ew[col];
                xb[(size_t)row * 512 + col] = f2bf(fmaxf(v, 0.0f));
            }
        }
    }
}

// =====================================================================
// K2: gated attention partial scores via MFMA on x_bf16 @ BagT.
// Wave col block blk = bxn*2+wc covers d in [blk*32, blk*32+32):
//   acc[mi][0]/[1] = a-pre for d0/d0+16, acc[mi][2]/[3] = g-pre.
// Epilogue: p = sum tanh(a)*sig(g)*Wc, 16-lane reduce, ps[blk][row].
// =====================================================================
__global__ __launch_bounds__(256) void gemm_ag_mfma(
    const ushort_t* __restrict__ xb, const ushort_t* __restrict__ bag,
    const float* __restrict__ bav, const float* __restrict__ bbv,
    const float* __restrict__ Wc, float* __restrict__ ps)
{
    __shared__ ushort_t As[128 * 32];
    __shared__ ushort_t Bs[128 * 32];

    const int t  = threadIdx.x;
    const int n0 = blockIdx.x * 128;
    const int m0 = blockIdx.y * 128;
    const int wid = t >> 6, wr = wid >> 1, wc = wid & 1;
    const int l  = t & 63, lr = l & 15, lg = l >> 4;

    const int r0 = t >> 2, ch = t & 3;
    const int swz = ((ch ^ ((r0 >> 1) & 3)) << 4);

    f32x4 acc[4][4] = {};

    const size_t aoff0 = ((size_t)(m0 + r0) * 512) + ch * 8;
    const size_t aoff1 = ((size_t)(m0 + 64 + r0) * 512) + ch * 8;
    const size_t boff0 = ((size_t)(n0 + r0) * 512) + ch * 8;
    const size_t boff1 = ((size_t)(n0 + 64 + r0) * 512) + ch * 8;

    ushortx8 sa0 = *(const ushortx8*)(xb + aoff0);
    ushortx8 sa1 = *(const ushortx8*)(xb + aoff1);
    ushortx8 sb0 = *(const ushortx8*)(bag + boff0);
    ushortx8 sb1 = *(const ushortx8*)(bag + boff1);

    for (int kt = 0; kt < 16; ++kt) {
        __syncthreads();
        *(ushortx8*)((char*)As + r0 * 64 + swz)        = sa0;
        *(ushortx8*)((char*)As + (64 + r0) * 64 + swz) = sa1;
        *(ushortx8*)((char*)Bs + r0 * 64 + swz)        = sb0;
        *(ushortx8*)((char*)Bs + (64 + r0) * 64 + swz) = sb1;
        __syncthreads();
        if (kt < 15) {
            int k = (kt + 1) * 32;
            sa0 = *(const ushortx8*)(xb + aoff0 + k);
            sa1 = *(const ushortx8*)(xb + aoff1 + k);
            sb0 = *(const ushortx8*)(bag + boff0 + k);
            sb1 = *(const ushortx8*)(bag + boff1 + k);
        }
        bf16x8 af[4], bg[4];
#pragma unroll
        for (int mi = 0; mi < 4; ++mi) {
            int R = wr * 64 + mi * 16 + lr;
            af[mi] = *(const bf16x8*)((const char*)As + R * 64 + ((lg ^ ((R >> 1) & 3)) << 4));
        }
#pragma unroll
        for (int ni = 0; ni < 4; ++ni) {
            int Cc = wc * 64 + ni * 16 + lr;
            bg[ni] = *(const bf16x8*)((const char*)Bs + Cc * 64 + ((lg ^ ((Cc >> 1) & 3)) << 4));
        }
#pragma unroll
        for (int mi = 0; mi < 4; ++mi)
#pragma unroll
            for (int ni = 0; ni < 4; ++ni)
                acc[mi][ni] = __builtin_amdgcn_mfma_f32_16x16x32_bf16(af[mi], bg[ni], acc[mi][ni], 0, 0, 0);
    }

    const int blk = blockIdx.x * 2 + wc;          // 0..7
    const int d0 = blk * 32 + lr, d1 = d0 + 16;
    const float ba0 = bav[d0], ba1 = bav[d1];
    const float bb0 = bbv[d0], bb1 = bbv[d1];
    const float w0 = Wc[d0],  w1 = Wc[d1];

#pragma unroll
    for (int mi = 0; mi < 4; ++mi) {
#pragma unroll
        for (int r = 0; r < 4; ++r) {
            float p = tanhf(acc[mi][0][r] + ba0) * sigf(acc[mi][2][r] + bb0) * w0
                    + tanhf(acc[mi][1][r] + ba1) * sigf(acc[mi][3][r] + bb1) * w1;
            p += __shfl_xor(p, 1); p += __shfl_xor(p, 2);
            p += __shfl_xor(p, 4); p += __shfl_xor(p, 8);
            if (lr == 0)
                ps[(size_t)blk * M_ + m0 + wr * 64 + mi * 16 + lg * 4 + r] = p;
        }
    }
}

// K3: s[m] = sum of 8 d-block partials + bc
__global__ void s_combine_kernel(const float* __restrict__ ps,
                                 const float* __restrict__ bc,
                                 float* __restrict__ s)
{
    int m = blockIdx.x * 256 + threadIdx.x;
    float v = bc[0];
#pragma unroll
    for (int b = 0; b < 8; ++b) v += ps[(size_t)b * M_ + m];
    s[m] = v;
}

// K4: per-(b,c) segment max and 1/sumexp
__global__ __launch_bounds__(256) void stats_kernel(
    const float* __restrict__ s, const int* __restrict__ cid,
    float* __restrict__ stat)
{
    __shared__ float red[256];
    const int b = blockIdx.x / C_;
    const int c = blockIdx.x % C_;
    const int t = threadIdx.x;

    float mx = -3.0e38f;
    for (int n = t; n < N_; n += 256)
        if (cid[b * N_ + n] == c) mx = fmaxf(mx, s[b * N_ + n]);
    red[t] = mx; __syncthreads();
    for (int off = 128; off > 0; off >>= 1) {
        if (t < off) red[t] = fmaxf(red[t], red[t + off]);
        __syncthreads();
    }
    mx = red[0]; __syncthreads();

    float sum = 0.f;
    for (int n = t; n < N_; n += 256)
        if (cid[b * N_ + n] == c) sum += expf(s[b * N_ + n] - mx);
    red[t] = sum; __syncthreads();
    for (int off = 128; off > 0; off >>= 1) {
        if (t < off) red[t] += red[t + off];
        __syncthreads();
    }
    if (t == 0) {
        stat[blockIdx.x]      = mx;
        stat[80 + blockIdx.x] = 1.0f / red[0];
    }
}

// K5a: per-row softmax weight
__global__ void weight_kernel(const float* __restrict__ s, const int* __restrict__ cid,
                              const float* __restrict__ stat, float* __restrict__ w)
{
    int m = blockIdx.x * 256 + threadIdx.x;
    int b = m >> 13;
    int c = cid[m];
    w[m] = expf(s[m] - stat[b * C_ + c]) * stat[80 + b * C_ + c];
}

// K5b: segmented weighted sums into per-chunk partials (x in bf16)
__global__ __launch_bounds__(256) void cpart_kernel(
    const ushort_t* __restrict__ xb, const int* __restrict__ cid,
    const float* __restrict__ w, float* __restrict__ cpart)
{
    __shared__ float acc[C_][512];
    const int b     = blockIdx.x >> 5;
    const int chunk = blockIdx.x & 31;
    const int t     = threadIdx.x;

#pragma unroll
    for (int c = 0; c < C_; ++c) { acc[c][t] = 0.f; acc[c][t + 256] = 0.f; }
    __syncthreads();

    const int base = b * N_ + chunk * 256;
    for (int r = 0; r < 256; ++r) {
        int m = base + r;
        int c = cid[m];
        float wv = w[m];
        acc[c][t]       += wv * bf2f(xb[(size_t)m * 512 + t]);
        acc[c][t + 256] += wv * bf2f(xb[(size_t)m * 512 + 256 + t]);
    }
    __syncthreads();
#pragma unroll
    for (int c = 0; c < C_; ++c) {
        size_t o = (((size_t)blockIdx.x) * C_ + c) * 512;
        cpart[o + t]       = acc[c][t];
        cpart[o + 256 + t] = acc[c][t + 256];
    }
}

// K6a: reduce 32 chunks -> cfeat[b,c,i]
__global__ void creduce_kernel(const float* __restrict__ cpart, float* __restrict__ cfeat)
{
    int o = blockIdx.x * 256 + threadIdx.x;   // < 80*512
    int i = o & 511;
    int bc = o >> 9;
    int b = bc / C_, c = bc % C_;
    float sum = 0.f;
    for (int ch = 0; ch < 32; ++ch)
        sum += cpart[(((size_t)(b * 32 + ch)) * C_ + c) * 512 + i];
    cfeat[o] = sum;
}

// K6b: cfeat2 = relu(cfeat @ Wfc + bfc)   (80 rows)
__global__ __launch_bounds__(256) void intra_fc_kernel(
    const float* __restrict__ cfeat, const float* __restrict__ Wfc,
    const float* __restrict__ bfc, float* __restrict__ cfeat2)
{
    __shared__ float row[512];
    const int bc = blockIdx.x;
    const int t  = threadIdx.x;
    row[t] = cfeat[bc * 512 + t]; row[t + 256] = cfeat[bc * 512 + 256 + t];
    __syncthreads();
    float a0 = 0.f, a1 = 0.f;
    for (int i = 0; i < 512; ++i) {
        float rv = row[i];
        a0 += rv * Wfc[(size_t)i * 512 + t];
        a1 += rv * Wfc[(size_t)i * 512 + 256 + t];
    }
    cfeat2[bc * 512 + t]       = fmaxf(a0 + bfc[t], 0.f);
    cfeat2[bc * 512 + 256 + t] = fmaxf(a1 + bfc[256 + t], 0.f);
}

// K7: inter-cluster gated attention scores s2[b,c]
__global__ __launch_bounds__(256) void inter_score_kernel(
    const float* __restrict__ cfeat2,
    const float* __restrict__ Wa2, const float* __restrict__ ba2,
    const float* __restrict__ Wb2, const float* __restrict__ bb2,
    const float* __restrict__ Wc2, const float* __restrict__ bc2,
    float* __restrict__ s2)
{
    __shared__ float row[512];
    __shared__ float red[256];
    const int bc = blockIdx.x;
    const int t  = threadIdx.x;
    row[t] = cfeat2[bc * 512 + t]; row[t + 256] = cfeat2[bc * 512 + 256 + t];
    __syncthreads();
    float pa = 0.f, pg = 0.f;
    for (int f = 0; f < 512; ++f) {
        float rv = row[f];
        pa += rv * Wa2[(size_t)f * 256 + t];
        pg += rv * Wb2[(size_t)f * 256 + t];
    }
    float v = tanhf(pa + ba2[t]) * sigf(pg + bb2[t]) * Wc2[t];
    red[t] = v; __syncthreads();
    for (int off = 128; off > 0; off >>= 1) {
        if (t < off) red[t] += red[t + off];
        __syncthreads();
    }
    if (t == 0) s2[bc] = red[0] + bc2[0];
}

// K8: softmax over C, slide pooling, final fc + classifier
__global__ __launch_bounds__(256) void final_kernel(
    const float* __restrict__ cfeat2, const float* __restrict__ s2,
    const float* __restrict__ Wfc2, const float* __restrict__ bfc2,
    const float* __restrict__ Wcls, const float* __restrict__ bcls,
    float* __restrict__ out)
{
    __shared__ float A2[C_];
    __shared__ float slide[512];
    __shared__ float slide2[256];
    const int b = blockIdx.x;
    const int t = threadIdx.x;

    if (t < C_) A2[t] = s2[b * C_ + t];
    __syncthreads();
    float mx = -3.0e38f;
    for (int c = 0; c < C_; ++c) mx = fmaxf(mx, A2[c]);
    float sum = 0.f;
    for (int c = 0; c < C_; ++c) sum += expf(A2[c] - mx);
    __syncthreads();
    if (t < C_) A2[t] = expf(A2[t] - mx) / sum;
    __syncthreads();

    float s0 = 0.f, s1 = 0.f;
    for (int c = 0; c < C_; ++c) {
        float a = A2[c];
        s0 += a * cfeat2[(b * C_ + c) * 512 + t];
        s1 += a * cfeat2[(b * C_ + c) * 512 + 256 + t];
    }
    slide[t] = s0; slide[t + 256] = s1;
    __syncthreads();

    float acc = 0.f;
    for (int f = 0; f < 512; ++f) acc += slide[f] * Wfc2[(size_t)f * 256 + t];
    slide2[t] = fmaxf(acc + bfc2[t], 0.f);
    __syncthreads();

    if (t < NCLS_) {
        float lg = bcls[t];
        for (int o = 0; o < 256; ++o) lg += slide2[o] * Wcls[o * 2 + t];
        out[b * 2 + t] = lg;
    }
}

extern "C" void kernel_launch(void* const* d_in, const int* in_sizes, int n_in,
                              void* d_out, int out_size, void* d_ws, size_t ws_size,
                              hipStream_t stream)
{
    (void)in_sizes; (void)n_in; (void)out_size; (void)ws_size;
    const float* h    = (const float*)d_in[0];
    const int*   cid  = (const int*)  d_in[1];
    const float* emb  = (const float*)d_in[2];
    const float* Wf   = (const float*)d_in[3];
    const float* bf   = (const float*)d_in[4];
    const float* Wa   = (const float*)d_in[5];
    const float* ba   = (const float*)d_in[6];
    const float* Wb   = (const float*)d_in[7];
    const float* bb   = (const float*)d_in[8];
    const float* Wc   = (const float*)d_in[9];
    const float* bc   = (const float*)d_in[10];
    const float* Wfc  = (const float*)d_in[11];
    const float* bfc  = (const float*)d_in[12];
    const float* Wa2  = (const float*)d_in[13];
    const float* ba2  = (const float*)d_in[14];
    const float* Wb2  = (const float*)d_in[15];
    const float* bb2  = (const float*)d_in[16];
    const float* Wc2  = (const float*)d_in[17];
    const float* bc2  = (const float*)d_in[18];
    const float* Wfc2 = (const float*)d_in[19];
    const float* bfc2 = (const float*)d_in[20];
    const float* Wcls = (const float*)d_in[21];
    const float* bcls = (const float*)d_in[22];

    char* ws = (char*)d_ws;
    ushort_t* XB   = (ushort_t*)(ws + XB_OFF);
    ushort_t* HB   = (ushort_t*)(ws + HB_OFF);
    ushort_t* WFT  = (ushort_t*)(ws + WFT_OFF);
    ushort_t* BAG  = (ushort_t*)(ws + BAG_OFF);
    float* EMBW    = (float*)(ws + EMBW_OFF);
    float* PS      = (float*)(ws + PS_OFF);
    float* S       = (float*)(ws + S_OFF);
    float* STAT    = (float*)(ws + STAT_OFF);
    float* W       = (float*)(ws + W_OFF);
    float* CPART   = (float*)(ws + CP_OFF);
    float* CFEAT   = (float*)(ws + CF_OFF);
    float* CFEAT2  = (float*)(ws + CF2_OFF);
    float* S2      = (float*)(ws + S2_OFF);
    float* out     = (float*)d_out;

    conv_h_kernel<<<16384, 256, 0, stream>>>(h, HB);
    prep_wft_kernel<<<1024, 256, 0, stream>>>(Wf, WFT);
    prep_bag_kernel<<<1024, 256, 0, stream>>>(Wa, Wb, BAG);
    prep_embw_kernel<<<20, 256, 0, stream>>>(emb, Wf, bf, EMBW);

    gemm_x_mfma<<<dim3(4, 512), 256, 0, stream>>>(HB, cid, WFT, EMBW, XB);
    gemm_ag_mfma<<<dim3(4, 512), 256, 0, stream>>>(XB, BAG, ba, bb, Wc, PS);

    s_combine_kernel<<<256, 256, 0, stream>>>(PS, bc, S);
    stats_kernel<<<B_ * C_, 256, 0, stream>>>(S, cid, STAT);
    weight_kernel<<<256, 256, 0, stream>>>(S, cid, STAT, W);
    cpart_kernel<<<B_ * 32, 256, 0, stream>>>(XB, cid, W, CPART);
    creduce_kernel<<<160, 256, 0, stream>>>(CPART, CFEAT);
    intra_fc_kernel<<<B_ * C_, 256, 0, stream>>>(CFEAT, Wfc, bfc, CFEAT2);
    inter_score_kernel<<<B_ * C_, 256, 0, stream>>>(CFEAT2, Wa2, ba2, Wb2, bb2, Wc2, bc2, S2);
    final_kernel<<<B_, 256, 0, stream>>>(CFEAT2, S2, Wfc2, bfc2, Wcls, bcls, out);
}

// Round 3
// 311.161 us; speedup vs baseline: 2.9370x; 1.1474x over previous
//
#include <hip/hip_runtime.h>
#include <math.h>

#define B_    8
#define N_    8192
#define M_    65536        // B_*N_
#define I_    512
#define E_    8
#define D_    256
#define C_    10
#define NCLS_ 2

typedef unsigned short ushort_t;
typedef ushort_t ushortx8 __attribute__((ext_vector_type(8)));
typedef __bf16   bf16x8  __attribute__((ext_vector_type(8)));
typedef float    f32x4   __attribute__((ext_vector_type(4)));

// ---------------- workspace layout (byte offsets) ----------------
static const size_t XB_OFF   = 0;                 // bf16 x [M_,512]
static const size_t HB_OFF   = 67108864;          // bf16 h [M_,512] (dead after gemm_x)
static const size_t WFT_OFF  = 134217728;         // bf16 WfT [512][512]
static const size_t BAG_OFF  = WFT_OFF + 524288;  // bf16 BagT [512][512]
static const size_t EMBW_OFF = BAG_OFF + 524288;  // f32 [10][512]
// overlap zone (inside HB, live only after gemm_x completes)
static const size_t PS_OFF   = HB_OFF;                    // 8*M_*4 = 2097152
static const size_t S_OFF    = PS_OFF + 2097152;          // M_*4
static const size_t STAT_OFF = S_OFF + 262144;            // 1024
static const size_t CP_OFF   = STAT_OFF + 1024;           // 512*10*512*4 = 10485760
static const size_t CF_OFF   = CP_OFF + 10485760;         // 80*512*4
static const size_t CF2_OFF  = CF_OFF + 163840;
static const size_t S2_OFF   = CF2_OFF + 163840;

__device__ __forceinline__ float sigf(float v) { return 1.0f / (1.0f + __expf(-v)); }

__device__ __forceinline__ ushort_t f2bf(float f) {
    union { float f; unsigned u; } v; v.f = f;
    unsigned r = v.u + 0x7FFF + ((v.u >> 16) & 1);   // RNE (finite data)
    return (ushort_t)(r >> 16);
}
__device__ __forceinline__ float bf2f(ushort_t u) {
    union { unsigned u; float f; } v; v.u = ((unsigned)u) << 16; return v.f;
}

// async global->LDS, 16B per lane; LDS dest is wave-uniform base + lane*16
__device__ __forceinline__ void gl_lds16(const ushort_t* g, ushort_t* l) {
    __builtin_amdgcn_global_load_lds(
        (const __attribute__((address_space(1))) void*)g,
        (__attribute__((address_space(3))) void*)l, 16, 0, 0);
}

// =====================================================================
// P1: convert h f32 -> bf16 (8 elems / thread)
// =====================================================================
__global__ __launch_bounds__(256) void conv_h_kernel(
    const float* __restrict__ h, ushort_t* __restrict__ hb)
{
    size_t i = (size_t)blockIdx.x * 256 + threadIdx.x;   // ushortx8 index
    const float4* h4 = (const float4*)h;
    float4 v0 = h4[i * 2], v1 = h4[i * 2 + 1];
    ushortx8 o;
    o[0] = f2bf(v0.x); o[1] = f2bf(v0.y); o[2] = f2bf(v0.z); o[3] = f2bf(v0.w);
    o[4] = f2bf(v1.x); o[5] = f2bf(v1.y); o[6] = f2bf(v1.z); o[7] = f2bf(v1.w);
    *(ushortx8*)(hb + i * 8) = o;
}

// P2: WfT[n][k] = bf16(Wf[k][n])  — coalesced read, scattered write
__global__ __launch_bounds__(256) void prep_wft_kernel(
    const float* __restrict__ Wf, ushort_t* __restrict__ wft)
{
    int idx = blockIdx.x * 256 + threadIdx.x;    // 0..262143
    int k = idx >> 9, n = idx & 511;
    wft[(size_t)n * 512 + k] = f2bf(Wf[(size_t)k * 512 + n]);
}

// P3: BagT: col blk*64+w (w<32: Wa col blk*32+w; w>=32: Wb col blk*32+w-32)
__global__ __launch_bounds__(256) void prep_bag_kernel(
    const float* __restrict__ Wa, const float* __restrict__ Wb,
    ushort_t* __restrict__ bag)
{
    int idx = blockIdx.x * 256 + threadIdx.x;    // 0..131071 : (k, d)
    int k = idx >> 8, d = idx & 255;
    float a = Wa[(size_t)k * 256 + d];
    float g = Wb[(size_t)k * 256 + d];
    int blk = d >> 5, w = d & 31;
    bag[(size_t)(blk * 64 + w) * 512 + k]      = f2bf(a);
    bag[(size_t)(blk * 64 + 32 + w) * 512 + k] = f2bf(g);
}

// P4: embW[c][n] = bf[n] + sum_e emb[c][e]*Wf[512+e][n]   (f32, 10x512)
__global__ __launch_bounds__(256) void prep_embw_kernel(
    const float* __restrict__ emb, const float* __restrict__ Wf,
    const float* __restrict__ bfv, float* __restrict__ embW)
{
    int idx = blockIdx.x * 256 + threadIdx.x;    // < 5120
    int c = idx >> 9, n = idx & 511;
    float s = bfv[n];
#pragma unroll
    for (int e = 0; e < 8; ++e) s += emb[c * 8 + e] * Wf[(size_t)(512 + e) * 512 + n];
    embW[(size_t)c * 512 + n] = s;
}

// =====================================================================
// K1: x = relu(h@Wf[:512] + embW[cid]) -> bf16.  128x128 tile, BK=32,
// m97 structure: global_load_lds(16B) staging, linear LDS dest with
// pre-swizzled global source (content: LDS[row][c] = g[row][c^((row>>1)&3)]),
// double-buffered, one __syncthreads (implicit vmcnt(0) drain) per K-step.
// =====================================================================
__global__ __launch_bounds__(256) void gemm_x_mfma(
    const ushort_t* __restrict__ hb, const int* __restrict__ cid,
    const ushort_t* __restrict__ wft, const float* __restrict__ embW,
    ushort_t* __restrict__ xb)
{
    __shared__ ushort_t As[2][128 * 32];
    __shared__ ushort_t Bs[2][128 * 32];

    const int t = threadIdx.x;
    // XCD-aware bijective swizzle (nwg = 2048 = 8*256)
    const int lin = blockIdx.y * 4 + blockIdx.x;
    const int swz = (lin & 7) * 256 + (lin >> 3);
    const int n0 = (swz & 3) * 128;
    const int m0 = (swz >> 2) * 128;

    const int wid = t >> 6, wr = wid >> 1, wc = wid & 1;
    const int l = t & 63, lr = l & 15, lg = l >> 4;

    const int srow = l >> 2;                          // row within 16-row stripe
    const int gch  = ((l & 3) ^ ((l >> 3) & 3)) * 8;  // pre-swizzled source chunk

    // wave wid stages stripes {2*wid, 2*wid+1} of A and of B
    const size_t gA0 = (size_t)(m0 + wid * 32 + srow) * 512 + gch;
    const size_t gA1 = gA0 + 16 * 512;
    const size_t gB0 = (size_t)(n0 + wid * 32 + srow) * 512 + gch;
    const size_t gB1 = gB0 + 16 * 512;
    ushort_t* lA = &As[0][wid * 1024];
    ushort_t* lB = &Bs[0][wid * 1024];

    f32x4 acc[4][4] = {};

#define STAGE_X(buf, kt) do { \
    size_t ko = (size_t)(kt) * 32; \
    gl_lds16(hb + gA0 + ko,  lA + (buf) * 4096); \
    gl_lds16(hb + gA1 + ko,  lA + (buf) * 4096 + 512); \
    gl_lds16(wft + gB0 + ko, lB + (buf) * 4096); \
    gl_lds16(wft + gB1 + ko, lB + (buf) * 4096 + 512); \
} while (0)

    STAGE_X(0, 0);
    __syncthreads();
    int cur = 0;
    for (int kt = 0; kt < 16; ++kt) {
        if (kt < 15) STAGE_X(cur ^ 1, kt + 1);
        const char* Ab = (const char*)&As[cur][0];
        const char* Bb = (const char*)&Bs[cur][0];
        bf16x8 af[4], bg[4];
#pragma unroll
        for (int mi = 0; mi < 4; ++mi) {
            int R = wr * 64 + mi * 16 + lr;
            af[mi] = *(const bf16x8*)(Ab + R * 64 + ((lg ^ ((R >> 1) & 3)) << 4));
        }
#pragma unroll
        for (int ni = 0; ni < 4; ++ni) {
            int Cc = wc * 64 + ni * 16 + lr;
            bg[ni] = *(const bf16x8*)(Bb + Cc * 64 + ((lg ^ ((Cc >> 1) & 3)) << 4));
        }
#pragma unroll
        for (int mi = 0; mi < 4; ++mi)
#pragma unroll
            for (int ni = 0; ni < 4; ++ni)
                acc[mi][ni] = __builtin_amdgcn_mfma_f32_16x16x32_bf16(af[mi], bg[ni], acc[mi][ni], 0, 0, 0);
        __syncthreads();   // implicit vmcnt(0): next tile staged & visible
        cur ^= 1;
    }

    // epilogue: + embW[cid[row]][col], relu, bf16 store
#pragma unroll
    for (int mi = 0; mi < 4; ++mi) {
#pragma unroll
        for (int r = 0; r < 4; ++r) {
            int row = m0 + wr * 64 + mi * 16 + lg * 4 + r;
            const float* ew = embW + (size_t)cid[row] * 512;
#pragma unroll
            for (int ni = 0; ni < 4; ++ni) {
                int col = n0 + wc * 64 + ni * 16 + lr;
                float v = acc[mi][ni][r] + ew[col];
                xb[(size_t)row * 512 + col] = f2bf(fmaxf(v, 0.0f));
            }
        }
    }
}

// =====================================================================
// K2: gated attention partial scores, same m97 structure.
// =====================================================================
__global__ __launch_bounds__(256) void gemm_ag_mfma(
    const ushort_t* __restrict__ xb, const ushort_t* __restrict__ bag,
    const float* __restrict__ bav, const float* __restrict__ bbv,
    const float* __restrict__ Wc, float* __restrict__ ps)
{
    __shared__ ushort_t As[2][128 * 32];
    __shared__ ushort_t Bs[2][128 * 32];

    const int t = threadIdx.x;
    const int lin = blockIdx.y * 4 + blockIdx.x;
    const int swz = (lin & 7) * 256 + (lin >> 3);
    const int bxn = swz & 3;
    const int n0 = bxn * 128;
    const int m0 = (swz >> 2) * 128;

    const int wid = t >> 6, wr = wid >> 1, wc = wid & 1;
    const int l = t & 63, lr = l & 15, lg = l >> 4;

    const int srow = l >> 2;
    const int gch  = ((l & 3) ^ ((l >> 3) & 3)) * 8;

    const size_t gA0 = (size_t)(m0 + wid * 32 + srow) * 512 + gch;
    const size_t gA1 = gA0 + 16 * 512;
    const size_t gB0 = (size_t)(n0 + wid * 32 + srow) * 512 + gch;
    const size_t gB1 = gB0 + 16 * 512;
    ushort_t* lA = &As[0][wid * 1024];
    ushort_t* lB = &Bs[0][wid * 1024];

    f32x4 acc[4][4] = {};

#define STAGE_AG(buf, kt) do { \
    size_t ko = (size_t)(kt) * 32; \
    gl_lds16(xb + gA0 + ko,  lA + (buf) * 4096); \
    gl_lds16(xb + gA1 + ko,  lA + (buf) * 4096 + 512); \
    gl_lds16(bag + gB0 + ko, lB + (buf) * 4096); \
    gl_lds16(bag + gB1 + ko, lB + (buf) * 4096 + 512); \
} while (0)

    STAGE_AG(0, 0);
    __syncthreads();
    int cur = 0;
    for (int kt = 0; kt < 16; ++kt) {
        if (kt < 15) STAGE_AG(cur ^ 1, kt + 1);
        const char* Ab = (const char*)&As[cur][0];
        const char* Bb = (const char*)&Bs[cur][0];
        bf16x8 af[4], bg[4];
#pragma unroll
        for (int mi = 0; mi < 4; ++mi) {
            int R = wr * 64 + mi * 16 + lr;
            af[mi] = *(const bf16x8*)(Ab + R * 64 + ((lg ^ ((R >> 1) & 3)) << 4));
        }
#pragma unroll
        for (int ni = 0; ni < 4; ++ni) {
            int Cc = wc * 64 + ni * 16 + lr;
            bg[ni] = *(const bf16x8*)(Bb + Cc * 64 + ((lg ^ ((Cc >> 1) & 3)) << 4));
        }
#pragma unroll
        for (int mi = 0; mi < 4; ++mi)
#pragma unroll
            for (int ni = 0; ni < 4; ++ni)
                acc[mi][ni] = __builtin_amdgcn_mfma_f32_16x16x32_bf16(af[mi], bg[ni], acc[mi][ni], 0, 0, 0);
        __syncthreads();
        cur ^= 1;
    }

    // epilogue: wave col block blk covers d in [blk*32, blk*32+32)
    const int blk = bxn * 2 + wc;                 // 0..7
    const int d0 = blk * 32 + lr, d1 = d0 + 16;
    const float ba0 = bav[d0], ba1 = bav[d1];
    const float bb0 = bbv[d0], bb1 = bbv[d1];
    const float w0 = Wc[d0],  w1 = Wc[d1];

#pragma unroll
    for (int mi = 0; mi < 4; ++mi) {
#pragma unroll
        for (int r = 0; r < 4; ++r) {
            float p = tanhf(acc[mi][0][r] + ba0) * sigf(acc[mi][2][r] + bb0) * w0
                    + tanhf(acc[mi][1][r] + ba1) * sigf(acc[mi][3][r] + bb1) * w1;
            p += __shfl_xor(p, 1); p += __shfl_xor(p, 2);
            p += __shfl_xor(p, 4); p += __shfl_xor(p, 8);
            if (lr == 0)
                ps[(size_t)blk * M_ + m0 + wr * 64 + mi * 16 + lg * 4 + r] = p;
        }
    }
}

// K3: s[m] = sum of 8 d-block partials + bc
__global__ void s_combine_kernel(const float* __restrict__ ps,
                                 const float* __restrict__ bc,
                                 float* __restrict__ s)
{
    int m = blockIdx.x * 256 + threadIdx.x;
    float v = bc[0];
#pragma unroll
    for (int b = 0; b < 8; ++b) v += ps[(size_t)b * M_ + m];
    s[m] = v;
}

// K4: per-(b,c) segment max and 1/sumexp
__global__ __launch_bounds__(256) void stats_kernel(
    const float* __restrict__ s, const int* __restrict__ cid,
    float* __restrict__ stat)
{
    __shared__ float red[256];
    const int b = blockIdx.x / C_;
    const int c = blockIdx.x % C_;
    const int t = threadIdx.x;

    float mx = -3.0e38f;
    for (int n = t; n < N_; n += 256)
        if (cid[b * N_ + n] == c) mx = fmaxf(mx, s[b * N_ + n]);
    red[t] = mx; __syncthreads();
    for (int off = 128; off > 0; off >>= 1) {
        if (t < off) red[t] = fmaxf(red[t], red[t + off]);
        __syncthreads();
    }
    mx = red[0]; __syncthreads();

    float sum = 0.f;
    for (int n = t; n < N_; n += 256)
        if (cid[b * N_ + n] == c) sum += expf(s[b * N_ + n] - mx);
    red[t] = sum; __syncthreads();
    for (int off = 128; off > 0; off >>= 1) {
        if (t < off) red[t] += red[t + off];
        __syncthreads();
    }
    if (t == 0) {
        stat[blockIdx.x]      = mx;
        stat[80 + blockIdx.x] = 1.0f / red[0];
    }
}

// K5: segmented weighted sums, register accumulators, weight inline.
// 512 blocks: (b, chunk of 128 rows); thread t covers cols 2t, 2t+1.
__global__ __launch_bounds__(256) void cpart_kernel(
    const ushort_t* __restrict__ xb, const int* __restrict__ cid,
    const float* __restrict__ s, const float* __restrict__ stat,
    float* __restrict__ cpart)
{
    const int b     = blockIdx.x >> 6;
    const int chunk = blockIdx.x & 63;
    const int t     = threadIdx.x;

    float2 acc[C_];
#pragma unroll
    for (int c = 0; c < C_; ++c) { acc[c].x = 0.f; acc[c].y = 0.f; }

    const int base = b * N_ + chunk * 128;
    for (int r = 0; r < 128; ++r) {
        int m = base + r;
        int c = cid[m];
        float wv = expf(s[m] - stat[b * C_ + c]) * stat[80 + b * C_ + c];
        unsigned xv = *(const unsigned*)(xb + (size_t)m * 512 + t * 2);
        float x0 = bf2f((ushort_t)(xv & 0xffff));
        float x1 = bf2f((ushort_t)(xv >> 16));
#pragma unroll
        for (int cc = 0; cc < C_; ++cc) {
            float w = (cc == c) ? wv : 0.0f;
            acc[cc].x += w * x0;
            acc[cc].y += w * x1;
        }
    }
#pragma unroll
    for (int cc = 0; cc < C_; ++cc)
        *(float2*)(&cpart[(((size_t)blockIdx.x) * C_ + cc) * 512 + t * 2]) = acc[cc];
}

// K6a: reduce 64 chunks -> cfeat[b,c,i]
__global__ void creduce_kernel(const float* __restrict__ cpart, float* __restrict__ cfeat)
{
    int o = blockIdx.x * 256 + threadIdx.x;   // < 80*512
    int i = o & 511;
    int bc = o >> 9;
    int b = bc / C_, c = bc % C_;
    float sum = 0.f;
    for (int ch = 0; ch < 64; ++ch)
        sum += cpart[(((size_t)(b * 64 + ch)) * C_ + c) * 512 + i];
    cfeat[o] = sum;
}

// K6b: cfeat2 = relu(cfeat @ Wfc + bfc)   (80 rows)
__global__ __launch_bounds__(256) void intra_fc_kernel(
    const float* __restrict__ cfeat, const float* __restrict__ Wfc,
    const float* __restrict__ bfc, float* __restrict__ cfeat2)
{
    __shared__ float row[512];
    const int bc = blockIdx.x;
    const int t  = threadIdx.x;
    row[t] = cfeat[bc * 512 + t]; row[t + 256] = cfeat[bc * 512 + 256 + t];
    __syncthreads();
    float a0 = 0.f, a1 = 0.f;
    for (int i = 0; i < 512; ++i) {
        float rv = row[i];
        a0 += rv * Wfc[(size_t)i * 512 + t];
        a1 += rv * Wfc[(size_t)i * 512 + 256 + t];
    }
    cfeat2[bc * 512 + t]       = fmaxf(a0 + bfc[t], 0.f);
    cfeat2[bc * 512 + 256 + t] = fmaxf(a1 + bfc[256 + t], 0.f);
}

// K7: inter-cluster gated attention scores s2[b,c]
__global__ __launch_bounds__(256) void inter_score_kernel(
    const float* __restrict__ cfeat2,
    const float* __restrict__ Wa2, const float* __restrict__ ba2,
    const float* __restrict__ Wb2, const float* __restrict__ bb2,
    const float* __restrict__ Wc2, const float* __restrict__ bc2,
    float* __restrict__ s2)
{
    __shared__ float row[512];
    __shared__ float red[256];
    const int bc = blockIdx.x;
    const int t  = threadIdx.x;
    row[t] = cfeat2[bc * 512 + t]; row[t + 256] = cfeat2[bc * 512 + 256 + t];
    __syncthreads();
    float pa = 0.f, pg = 0.f;
    for (int f = 0; f < 512; ++f) {
        float rv = row[f];
        pa += rv * Wa2[(size_t)f * 256 + t];
        pg += rv * Wb2[(size_t)f * 256 + t];
    }
    float v = tanhf(pa + ba2[t]) * sigf(pg + bb2[t]) * Wc2[t];
    red[t] = v; __syncthreads();
    for (int off = 128; off > 0; off >>= 1) {
        if (t < off) red[t] += red[t + off];
        __syncthreads();
    }
    if (t == 0) s2[bc] = red[0] + bc2[0];
}

// K8: softmax over C, slide pooling, final fc + classifier
__global__ __launch_bounds__(256) void final_kernel(
    const float* __restrict__ cfeat2, const float* __restrict__ s2,
    const float* __restrict__ Wfc2, const float* __restrict__ bfc2,
    const float* __restrict__ Wcls, const float* __restrict__ bcls,
    float* __restrict__ out)
{
    __shared__ float A2[C_];
    __shared__ float slide[512];
    __shared__ float slide2[256];
    const int b = blockIdx.x;
    const int t = threadIdx.x;

    if (t < C_) A2[t] = s2[b * C_ + t];
    __syncthreads();
    float mx = -3.0e38f;
    for (int c = 0; c < C_; ++c) mx = fmaxf(mx, A2[c]);
    float sum = 0.f;
    for (int c = 0; c < C_; ++c) sum += expf(A2[c] - mx);
    __syncthreads();
    if (t < C_) A2[t] = expf(A2[t] - mx) / sum;
    __syncthreads();

    float s0 = 0.f, s1 = 0.f;
    for (int c = 0; c < C_; ++c) {
        float a = A2[c];
        s0 += a * cfeat2[(b * C_ + c) * 512 + t];
        s1 += a * cfeat2[(b * C_ + c) * 512 + 256 + t];
    }
    slide[t] = s0; slide[t + 256] = s1;
    __syncthreads();

    float acc = 0.f;
    for (int f = 0; f < 512; ++f) acc += slide[f] * Wfc2[(size_t)f * 256 + t];
    slide2[t] = fmaxf(acc + bfc2[t], 0.f);
    __syncthreads();

    if (t < NCLS_) {
        float lg = bcls[t];
        for (int o = 0; o < 256; ++o) lg += slide2[o] * Wcls[o * 2 + t];
        out[b * 2 + t] = lg;
    }
}

extern "C" void kernel_launch(void* const* d_in, const int* in_sizes, int n_in,
                              void* d_out, int out_size, void* d_ws, size_t ws_size,
                              hipStream_t stream)
{
    (void)in_sizes; (void)n_in; (void)out_size; (void)ws_size;
    const float* h    = (const float*)d_in[0];
    const int*   cid  = (const int*)  d_in[1];
    const float* emb  = (const float*)d_in[2];
    const float* Wf   = (const float*)d_in[3];
    const float* bf   = (const float*)d_in[4];
    const float* Wa   = (const float*)d_in[5];
    const float* ba   = (const float*)d_in[6];
    const float* Wb   = (const float*)d_in[7];
    const float* bb   = (const float*)d_in[8];
    const float* Wc   = (const float*)d_in[9];
    const float* bc   = (const float*)d_in[10];
    const float* Wfc  = (const float*)d_in[11];
    const float* bfc  = (const float*)d_in[12];
    const float* Wa2  = (const float*)d_in[13];
    const float* ba2  = (const float*)d_in[14];
    const float* Wb2  = (const float*)d_in[15];
    const float* bb2  = (const float*)d_in[16];
    const float* Wc2  = (const float*)d_in[17];
    const float* bc2  = (const float*)d_in[18];
    const float* Wfc2 = (const float*)d_in[19];
    const float* bfc2 = (const float*)d_in[20];
    const float* Wcls = (const float*)d_in[21];
    const float* bcls = (const float*)d_in[22];

    char* ws = (char*)d_ws;
    ushort_t* XB   = (ushort_t*)(ws + XB_OFF);
    ushort_t* HB   = (ushort_t*)(ws + HB_OFF);
    ushort_t* WFT  = (ushort_t*)(ws + WFT_OFF);
    ushort_t* BAG  = (ushort_t*)(ws + BAG_OFF);
    float* EMBW    = (float*)(ws + EMBW_OFF);
    float* PS      = (float*)(ws + PS_OFF);
    float* S       = (float*)(ws + S_OFF);
    float* STAT    = (float*)(ws + STAT_OFF);
    float* CPART   = (float*)(ws + CP_OFF);
    float* CFEAT   = (float*)(ws + CF_OFF);
    float* CFEAT2  = (float*)(ws + CF2_OFF);
    float* S2      = (float*)(ws + S2_OFF);
    float* out     = (float*)d_out;

    conv_h_kernel<<<16384, 256, 0, stream>>>(h, HB);
    prep_wft_kernel<<<1024, 256, 0, stream>>>(Wf, WFT);
    prep_bag_kernel<<<512, 256, 0, stream>>>(Wa, Wb, BAG);
    prep_embw_kernel<<<20, 256, 0, stream>>>(emb, Wf, bf, EMBW);

    gemm_x_mfma<<<dim3(4, 512), 256, 0, stream>>>(HB, cid, WFT, EMBW, XB);
    gemm_ag_mfma<<<dim3(4, 512), 256, 0, stream>>>(XB, BAG, ba, bb, Wc, PS);

    s_combine_kernel<<<256, 256, 0, stream>>>(PS, bc, S);
    stats_kernel<<<B_ * C_, 256, 0, stream>>>(S, cid, STAT);
    cpart_kernel<<<512, 256, 0, stream>>>(XB, cid, S, STAT, CPART);
    creduce_kernel<<<160, 256, 0, stream>>>(CPART, CFEAT);
    intra_fc_kernel<<<B_ * C_, 256, 0, stream>>>(CFEAT, Wfc, bfc, CFEAT2);
    inter_score_kernel<<<B_ * C_, 256, 0, stream>>>(CFEAT2, Wa2, ba2, Wb2, bb2, Wc2, bc2, S2);
    final_kernel<<<B_, 256, 0, stream>>>(CFEAT2, S2, Wfc2, bfc2, Wcls, bcls, out);
}

// Round 4
// 269.624 us; speedup vs baseline: 3.3895x; 1.1541x over previous
//
#include <hip/hip_runtime.h>
#include <math.h>

#define B_    8
#define N_    8192
#define M_    65536        // B_*N_
#define I_    512
#define E_    8
#define D_    256
#define C_    10
#define NCLS_ 2

typedef unsigned short ushort_t;
typedef ushort_t ushortx8 __attribute__((ext_vector_type(8)));
typedef __bf16   bf16x8  __attribute__((ext_vector_type(8)));
typedef float    f32x4   __attribute__((ext_vector_type(4)));

// ---------------- workspace layout (byte offsets) ----------------
static const size_t XB_OFF   = 0;                 // bf16 x [M_,512]
static const size_t HB_OFF   = 67108864;          // bf16 h [M_,512] (dead after gemm_x)
static const size_t WFT_OFF  = 134217728;         // bf16 WfT [512][512]
static const size_t BAG_OFF  = WFT_OFF + 524288;  // bf16 BagT [512][512]
static const size_t EMBW_OFF = BAG_OFF + 524288;  // f32 [10][512]
// overlap zone (inside HB, live only after gemm_x completes)
static const size_t PS_OFF   = HB_OFF;                    // 8*M_*4 = 2097152
static const size_t S_OFF    = PS_OFF + 2097152;          // M_*4
static const size_t STAT_OFF = S_OFF + 262144;            // 1024 (160 f32 used)
static const size_t PST_OFF  = STAT_OFF + 1024;           // 640*2*4 = 5120
static const size_t CP_OFF   = PST_OFF + 5120;            // 512*10*512*4 = 10485760
static const size_t CF_OFF   = CP_OFF + 10485760;         // 80*512*4
static const size_t CF2_OFF  = CF_OFF + 163840;
static const size_t S2_OFF   = CF2_OFF + 163840;

__device__ __forceinline__ float sigf(float v) { return 1.0f / (1.0f + __expf(-v)); }

__device__ __forceinline__ ushort_t f2bf(float f) {
    union { float f; unsigned u; } v; v.f = f;
    unsigned r = v.u + 0x7FFF + ((v.u >> 16) & 1);   // RNE (finite data)
    return (ushort_t)(r >> 16);
}
__device__ __forceinline__ float bf2f(ushort_t u) {
    union { unsigned u; float f; } v; v.u = ((unsigned)u) << 16; return v.f;
}

// async global->LDS, 16B per lane; LDS dest is wave-uniform base + lane*16
__device__ __forceinline__ void gl_lds16(const ushort_t* g, ushort_t* l) {
    __builtin_amdgcn_global_load_lds(
        (const __attribute__((address_space(1))) void*)g,
        (__attribute__((address_space(3))) void*)l, 16, 0, 0);
}

// =====================================================================
// P1: convert h f32 -> bf16 (8 elems / thread)
// =====================================================================
__global__ __launch_bounds__(256) void conv_h_kernel(
    const float* __restrict__ h, ushort_t* __restrict__ hb)
{
    size_t i = (size_t)blockIdx.x * 256 + threadIdx.x;   // ushortx8 index
    const float4* h4 = (const float4*)h;
    float4 v0 = h4[i * 2], v1 = h4[i * 2 + 1];
    ushortx8 o;
    o[0] = f2bf(v0.x); o[1] = f2bf(v0.y); o[2] = f2bf(v0.z); o[3] = f2bf(v0.w);
    o[4] = f2bf(v1.x); o[5] = f2bf(v1.y); o[6] = f2bf(v1.z); o[7] = f2bf(v1.w);
    *(ushortx8*)(hb + i * 8) = o;
}

// P2: WfT[n][k] = bf16(Wf[k][n])  — coalesced read, scattered write
__global__ __launch_bounds__(256) void prep_wft_kernel(
    const float* __restrict__ Wf, ushort_t* __restrict__ wft)
{
    int idx = blockIdx.x * 256 + threadIdx.x;    // 0..262143
    int k = idx >> 9, n = idx & 511;
    wft[(size_t)n * 512 + k] = f2bf(Wf[(size_t)k * 512 + n]);
}

// P3: BagT: col blk*64+w (w<32: Wa col blk*32+w; w>=32: Wb col blk*32+w-32)
__global__ __launch_bounds__(256) void prep_bag_kernel(
    const float* __restrict__ Wa, const float* __restrict__ Wb,
    ushort_t* __restrict__ bag)
{
    int idx = blockIdx.x * 256 + threadIdx.x;    // 0..131071 : (k, d)
    int k = idx >> 8, d = idx & 255;
    float a = Wa[(size_t)k * 256 + d];
    float g = Wb[(size_t)k * 256 + d];
    int blk = d >> 5, w = d & 31;
    bag[(size_t)(blk * 64 + w) * 512 + k]      = f2bf(a);
    bag[(size_t)(blk * 64 + 32 + w) * 512 + k] = f2bf(g);
}

// P4: embW[c][n] = bf[n] + sum_e emb[c][e]*Wf[512+e][n]   (f32, 10x512)
__global__ __launch_bounds__(256) void prep_embw_kernel(
    const float* __restrict__ emb, const float* __restrict__ Wf,
    const float* __restrict__ bfv, float* __restrict__ embW)
{
    int idx = blockIdx.x * 256 + threadIdx.x;    // < 5120
    int c = idx >> 9, n = idx & 511;
    float s = bfv[n];
#pragma unroll
    for (int e = 0; e < 8; ++e) s += emb[c * 8 + e] * Wf[(size_t)(512 + e) * 512 + n];
    embW[(size_t)c * 512 + n] = s;
}

// =====================================================================
// K1: x = relu(h@Wf[:512] + embW[cid]) -> bf16.
// BM=256 x BN=128 tile, BK=32, 512 threads = 8 waves (4M x 2N),
// wave tile 64x64 (identical per-wave code to the verified 128^2 version).
// global_load_lds(16B) staging (3/thread/K-step), linear LDS dest with
// pre-swizzled global source, double-buffered, one barrier per K-step.
// =====================================================================
__global__ __launch_bounds__(512) void gemm_x_mfma(
    const ushort_t* __restrict__ hb, const int* __restrict__ cid,
    const ushort_t* __restrict__ wft, const float* __restrict__ embW,
    ushort_t* __restrict__ xb)
{
    __shared__ ushort_t As[2][256 * 32];   // 32 KB
    __shared__ ushort_t Bs[2][128 * 32];   // 16 KB

    const int t = threadIdx.x;
    // XCD-aware bijective swizzle (nwg = 1024 = 8*128)
    const int lin = blockIdx.y * 4 + blockIdx.x;
    const int swz = (lin & 7) * 128 + (lin >> 3);
    const int n0 = (swz & 3) * 128;
    const int m0 = (swz >> 2) * 256;

    const int wid = t >> 6;                 // 0..7
    const int wr = wid >> 1, wc = wid & 1;  // 4M x 2N wave grid
    const int l = t & 63, lr = l & 15, lg = l >> 4;

    const int srow = l >> 2;                          // 0..15
    const int gch  = ((l & 3) ^ ((l >> 3) & 3)) * 8;  // pre-swizzled source chunk

    // wave wid stages A rows [wid*32, wid*32+32) and B rows [wid*16, wid*16+16)
    const size_t gA0 = (size_t)(m0 + wid * 32 + srow) * 512 + gch;
    const size_t gA1 = gA0 + 16 * 512;
    const size_t gB0 = (size_t)(n0 + wid * 16 + srow) * 512 + gch;
    ushort_t* lA = &As[0][wid * 1024];
    ushort_t* lB = &Bs[0][wid * 512];

    f32x4 acc[4][4] = {};

#define STAGE_X(buf, kt) do { \
    size_t ko = (size_t)(kt) * 32; \
    gl_lds16(hb + gA0 + ko,  lA + (buf) * 8192); \
    gl_lds16(hb + gA1 + ko,  lA + (buf) * 8192 + 512); \
    gl_lds16(wft + gB0 + ko, lB + (buf) * 4096); \
} while (0)

    STAGE_X(0, 0);
    __syncthreads();
    int cur = 0;
    for (int kt = 0; kt < 16; ++kt) {
        if (kt < 15) STAGE_X(cur ^ 1, kt + 1);
        const char* Ab = (const char*)&As[cur][0];
        const char* Bb = (const char*)&Bs[cur][0];
        bf16x8 af[4], bg[4];
#pragma unroll
        for (int mi = 0; mi < 4; ++mi) {
            int R = wr * 64 + mi * 16 + lr;
            af[mi] = *(const bf16x8*)(Ab + R * 64 + ((lg ^ ((R >> 1) & 3)) << 4));
        }
#pragma unroll
        for (int ni = 0; ni < 4; ++ni) {
            int Cc = wc * 64 + ni * 16 + lr;
            bg[ni] = *(const bf16x8*)(Bb + Cc * 64 + ((lg ^ ((Cc >> 1) & 3)) << 4));
        }
#pragma unroll
        for (int mi = 0; mi < 4; ++mi)
#pragma unroll
            for (int ni = 0; ni < 4; ++ni)
                acc[mi][ni] = __builtin_amdgcn_mfma_f32_16x16x32_bf16(af[mi], bg[ni], acc[mi][ni], 0, 0, 0);
        __syncthreads();   // implicit vmcnt(0): next tile staged & visible
        cur ^= 1;
    }

    // epilogue: + embW[cid[row]][col], relu, bf16 store
#pragma unroll
    for (int mi = 0; mi < 4; ++mi) {
#pragma unroll
        for (int r = 0; r < 4; ++r) {
            int row = m0 + wr * 64 + mi * 16 + lg * 4 + r;
            const float* ew = embW + (size_t)cid[row] * 512;
#pragma unroll
            for (int ni = 0; ni < 4; ++ni) {
                int col = n0 + wc * 64 + ni * 16 + lr;
                float v = acc[mi][ni][r] + ew[col];
                xb[(size_t)row * 512 + col] = f2bf(fmaxf(v, 0.0f));
            }
        }
    }
}

// =====================================================================
// K2: gated attention partial scores, same structure.
// =====================================================================
__global__ __launch_bounds__(512) void gemm_ag_mfma(
    const ushort_t* __restrict__ xb, const ushort_t* __restrict__ bag,
    const float* __restrict__ bav, const float* __restrict__ bbv,
    const float* __restrict__ Wc, float* __restrict__ ps)
{
    __shared__ ushort_t As[2][256 * 32];
    __shared__ ushort_t Bs[2][128 * 32];

    const int t = threadIdx.x;
    const int lin = blockIdx.y * 4 + blockIdx.x;
    const int swz = (lin & 7) * 128 + (lin >> 3);
    const int bxn = swz & 3;
    const int n0 = bxn * 128;
    const int m0 = (swz >> 2) * 256;

    const int wid = t >> 6;
    const int wr = wid >> 1, wc = wid & 1;
    const int l = t & 63, lr = l & 15, lg = l >> 4;

    const int srow = l >> 2;
    const int gch  = ((l & 3) ^ ((l >> 3) & 3)) * 8;

    const size_t gA0 = (size_t)(m0 + wid * 32 + srow) * 512 + gch;
    const size_t gA1 = gA0 + 16 * 512;
    const size_t gB0 = (size_t)(n0 + wid * 16 + srow) * 512 + gch;
    ushort_t* lA = &As[0][wid * 1024];
    ushort_t* lB = &Bs[0][wid * 512];

    f32x4 acc[4][4] = {};

#define STAGE_AG(buf, kt) do { \
    size_t ko = (size_t)(kt) * 32; \
    gl_lds16(xb + gA0 + ko,  lA + (buf) * 8192); \
    gl_lds16(xb + gA1 + ko,  lA + (buf) * 8192 + 512); \
    gl_lds16(bag + gB0 + ko, lB + (buf) * 4096); \
} while (0)

    STAGE_AG(0, 0);
    __syncthreads();
    int cur = 0;
    for (int kt = 0; kt < 16; ++kt) {
        if (kt < 15) STAGE_AG(cur ^ 1, kt + 1);
        const char* Ab = (const char*)&As[cur][0];
        const char* Bb = (const char*)&Bs[cur][0];
        bf16x8 af[4], bg[4];
#pragma unroll
        for (int mi = 0; mi < 4; ++mi) {
            int R = wr * 64 + mi * 16 + lr;
            af[mi] = *(const bf16x8*)(Ab + R * 64 + ((lg ^ ((R >> 1) & 3)) << 4));
        }
#pragma unroll
        for (int ni = 0; ni < 4; ++ni) {
            int Cc = wc * 64 + ni * 16 + lr;
            bg[ni] = *(const bf16x8*)(Bb + Cc * 64 + ((lg ^ ((Cc >> 1) & 3)) << 4));
        }
#pragma unroll
        for (int mi = 0; mi < 4; ++mi)
#pragma unroll
            for (int ni = 0; ni < 4; ++ni)
                acc[mi][ni] = __builtin_amdgcn_mfma_f32_16x16x32_bf16(af[mi], bg[ni], acc[mi][ni], 0, 0, 0);
        __syncthreads();
        cur ^= 1;
    }

    // epilogue: wave col block blk covers d in [blk*32, blk*32+32)
    const int blk = bxn * 2 + wc;                 // 0..7
    const int d0 = blk * 32 + lr, d1 = d0 + 16;
    const float ba0 = bav[d0], ba1 = bav[d1];
    const float bb0 = bbv[d0], bb1 = bbv[d1];
    const float w0 = Wc[d0],  w1 = Wc[d1];

#pragma unroll
    for (int mi = 0; mi < 4; ++mi) {
#pragma unroll
        for (int r = 0; r < 4; ++r) {
            float p = tanhf(acc[mi][0][r] + ba0) * sigf(acc[mi][2][r] + bb0) * w0
                    + tanhf(acc[mi][1][r] + ba1) * sigf(acc[mi][3][r] + bb1) * w1;
            p += __shfl_xor(p, 1); p += __shfl_xor(p, 2);
            p += __shfl_xor(p, 4); p += __shfl_xor(p, 8);
            if (lr == 0)
                ps[(size_t)blk * M_ + m0 + wr * 64 + mi * 16 + lg * 4 + r] = p;
        }
    }
}

// K3: s[m] = sum of 8 d-block partials + bc
__global__ void s_combine_kernel(const float* __restrict__ ps,
                                 const float* __restrict__ bc,
                                 float* __restrict__ s)
{
    int m = blockIdx.x * 256 + threadIdx.x;
    float v = bc[0];
#pragma unroll
    for (int b = 0; b < 8; ++b) v += ps[(size_t)b * M_ + m];
    s[m] = v;
}

// K4a: per-(b,c,slice) partial max & sum-exp (640 blocks, slices of 1024)
__global__ __launch_bounds__(256) void stats1_kernel(
    const float* __restrict__ s, const int* __restrict__ cid,
    float* __restrict__ pst)
{
    __shared__ float red[256];
    const int bc = blockIdx.x >> 3;            // 0..79
    const int sl = blockIdx.x & 7;
    const int b = bc / C_, c = bc % C_;
    const int t = threadIdx.x;
    const int base = b * N_ + sl * 1024;

    float mx = -3.0e38f;
    for (int i = t; i < 1024; i += 256)
        if (cid[base + i] == c) mx = fmaxf(mx, s[base + i]);
    red[t] = mx; __syncthreads();
    for (int off = 128; off > 0; off >>= 1) {
        if (t < off) red[t] = fmaxf(red[t], red[t + off]);
        __syncthreads();
    }
    mx = red[0]; __syncthreads();

    float sum = 0.f;
    for (int i = t; i < 1024; i += 256)
        if (cid[base + i] == c) sum += expf(s[base + i] - mx);
    red[t] = sum; __syncthreads();
    for (int off = 128; off > 0; off >>= 1) {
        if (t < off) red[t] += red[t + off];
        __syncthreads();
    }
    if (t == 0) {
        pst[blockIdx.x]       = mx;
        pst[640 + blockIdx.x] = red[0];
    }
}

// K4b: combine slice partials -> stat (max[80], 1/sumexp[80])
__global__ void stats2_kernel(const float* __restrict__ pst, float* __restrict__ stat)
{
    int t = threadIdx.x;
    if (t < 80) {
        float mx = -3.0e38f;
#pragma unroll
        for (int sl = 0; sl < 8; ++sl) mx = fmaxf(mx, pst[t * 8 + sl]);
        float sum = 0.f;
#pragma unroll
        for (int sl = 0; sl < 8; ++sl)
            sum += pst[640 + t * 8 + sl] * expf(pst[t * 8 + sl] - mx);
        stat[t]      = mx;
        stat[80 + t] = 1.0f / sum;
    }
}

// K5: segmented weighted sums; per-row weights precomputed in LDS once.
// 512 blocks: (b, chunk of 128 rows); thread t covers cols 2t, 2t+1.
__global__ __launch_bounds__(256) void cpart_kernel(
    const ushort_t* __restrict__ xb, const int* __restrict__ cid,
    const float* __restrict__ s, const float* __restrict__ stat,
    float* __restrict__ cpart)
{
    __shared__ float wrow[128];
    __shared__ int   crow[128];
    const int b     = blockIdx.x >> 6;
    const int chunk = blockIdx.x & 63;
    const int t     = threadIdx.x;
    const int base  = b * N_ + chunk * 128;

    if (t < 128) {
        int m = base + t;
        int c = cid[m];
        crow[t] = c;
        wrow[t] = expf(s[m] - stat[b * C_ + c]) * stat[80 + b * C_ + c];
    }
    __syncthreads();

    float2 acc[C_];
#pragma unroll
    for (int c = 0; c < C_; ++c) { acc[c].x = 0.f; acc[c].y = 0.f; }

    for (int r = 0; r < 128; ++r) {
        int c = crow[r];
        float wv = wrow[r];
        unsigned xv = *(const unsigned*)(xb + (size_t)(base + r) * 512 + t * 2);
        float x0 = bf2f((ushort_t)(xv & 0xffff));
        float x1 = bf2f((ushort_t)(xv >> 16));
#pragma unroll
        for (int cc = 0; cc < C_; ++cc) {
            float w = (cc == c) ? wv : 0.0f;
            acc[cc].x += w * x0;
            acc[cc].y += w * x1;
        }
    }
#pragma unroll
    for (int cc = 0; cc < C_; ++cc)
        *(float2*)(&cpart[(((size_t)blockIdx.x) * C_ + cc) * 512 + t * 2]) = acc[cc];
}

// K6a: reduce 64 chunks -> cfeat[b,c,i]
__global__ void creduce_kernel(const float* __restrict__ cpart, float* __restrict__ cfeat)
{
    int o = blockIdx.x * 256 + threadIdx.x;   // < 80*512
    int i = o & 511;
    int bc = o >> 9;
    int b = bc / C_, c = bc % C_;
    float sum = 0.f;
    for (int ch = 0; ch < 64; ++ch)
        sum += cpart[(((size_t)(b * 64 + ch)) * C_ + c) * 512 + i];
    cfeat[o] = sum;
}

// K6b: cfeat2 = relu(cfeat @ Wfc + bfc)   (80 rows)
__global__ __launch_bounds__(256) void intra_fc_kernel(
    const float* __restrict__ cfeat, const float* __restrict__ Wfc,
    const float* __restrict__ bfc, float* __restrict__ cfeat2)
{
    __shared__ float row[512];
    const int bc = blockIdx.x;
    const int t  = threadIdx.x;
    row[t] = cfeat[bc * 512 + t]; row[t + 256] = cfeat[bc * 512 + 256 + t];
    __syncthreads();
    float a0 = 0.f, a1 = 0.f;
    for (int i = 0; i < 512; ++i) {
        float rv = row[i];
        a0 += rv * Wfc[(size_t)i * 512 + t];
        a1 += rv * Wfc[(size_t)i * 512 + 256 + t];
    }
    cfeat2[bc * 512 + t]       = fmaxf(a0 + bfc[t], 0.f);
    cfeat2[bc * 512 + 256 + t] = fmaxf(a1 + bfc[256 + t], 0.f);
}

// K7: inter-cluster gated attention scores s2[b,c]
__global__ __launch_bounds__(256) void inter_score_kernel(
    const float* __restrict__ cfeat2,
    const float* __restrict__ Wa2, const float* __restrict__ ba2,
    const float* __restrict__ Wb2, const float* __restrict__ bb2,
    const float* __restrict__ Wc2, const float* __restrict__ bc2,
    float* __restrict__ s2)
{
    __shared__ float row[512];
    __shared__ float red[256];
    const int bc = blockIdx.x;
    const int t  = threadIdx.x;
    row[t] = cfeat2[bc * 512 + t]; row[t + 256] = cfeat2[bc * 512 + 256 + t];
    __syncthreads();
    float pa = 0.f, pg = 0.f;
    for (int f = 0; f < 512; ++f) {
        float rv = row[f];
        pa += rv * Wa2[(size_t)f * 256 + t];
        pg += rv * Wb2[(size_t)f * 256 + t];
    }
    float v = tanhf(pa + ba2[t]) * sigf(pg + bb2[t]) * Wc2[t];
    red[t] = v; __syncthreads();
    for (int off = 128; off > 0; off >>= 1) {
        if (t < off) red[t] += red[t + off];
        __syncthreads();
    }
    if (t == 0) s2[bc] = red[0] + bc2[0];
}

// K8: softmax over C, slide pooling, final fc + classifier
__global__ __launch_bounds__(256) void final_kernel(
    const float* __restrict__ cfeat2, const float* __restrict__ s2,
    const float* __restrict__ Wfc2, const float* __restrict__ bfc2,
    const float* __restrict__ Wcls, const float* __restrict__ bcls,
    float* __restrict__ out)
{
    __shared__ float A2[C_];
    __shared__ float slide[512];
    __shared__ float slide2[256];
    const int b = blockIdx.x;
    const int t = threadIdx.x;

    if (t < C_) A2[t] = s2[b * C_ + t];
    __syncthreads();
    float mx = -3.0e38f;
    for (int c = 0; c < C_; ++c) mx = fmaxf(mx, A2[c]);
    float sum = 0.f;
    for (int c = 0; c < C_; ++c) sum += expf(A2[c] - mx);
    __syncthreads();
    if (t < C_) A2[t] = expf(A2[t] - mx) / sum;
    __syncthreads();

    float s0 = 0.f, s1 = 0.f;
    for (int c = 0; c < C_; ++c) {
        float a = A2[c];
        s0 += a * cfeat2[(b * C_ + c) * 512 + t];
        s1 += a * cfeat2[(b * C_ + c) * 512 + 256 + t];
    }
    slide[t] = s0; slide[t + 256] = s1;
    __syncthreads();

    float acc = 0.f;
    for (int f = 0; f < 512; ++f) acc += slide[f] * Wfc2[(size_t)f * 256 + t];
    slide2[t] = fmaxf(acc + bfc2[t], 0.f);
    __syncthreads();

    if (t < NCLS_) {
        float lg = bcls[t];
        for (int o = 0; o < 256; ++o) lg += slide2[o] * Wcls[o * 2 + t];
        out[b * 2 + t] = lg;
    }
}

extern "C" void kernel_launch(void* const* d_in, const int* in_sizes, int n_in,
                              void* d_out, int out_size, void* d_ws, size_t ws_size,
                              hipStream_t stream)
{
    (void)in_sizes; (void)n_in; (void)out_size; (void)ws_size;
    const float* h    = (const float*)d_in[0];
    const int*   cid  = (const int*)  d_in[1];
    const float* emb  = (const float*)d_in[2];
    const float* Wf   = (const float*)d_in[3];
    const float* bf   = (const float*)d_in[4];
    const float* Wa   = (const float*)d_in[5];
    const float* ba   = (const float*)d_in[6];
    const float* Wb   = (const float*)d_in[7];
    const float* bb   = (const float*)d_in[8];
    const float* Wc   = (const float*)d_in[9];
    const float* bc   = (const float*)d_in[10];
    const float* Wfc  = (const float*)d_in[11];
    const float* bfc  = (const float*)d_in[12];
    const float* Wa2  = (const float*)d_in[13];
    const float* ba2  = (const float*)d_in[14];
    const float* Wb2  = (const float*)d_in[15];
    const float* bb2  = (const float*)d_in[16];
    const float* Wc2  = (const float*)d_in[17];
    const float* bc2  = (const float*)d_in[18];
    const float* Wfc2 = (const float*)d_in[19];
    const float* bfc2 = (const float*)d_in[20];
    const float* Wcls = (const float*)d_in[21];
    const float* bcls = (const float*)d_in[22];

    char* ws = (char*)d_ws;
    ushort_t* XB   = (ushort_t*)(ws + XB_OFF);
    ushort_t* HB   = (ushort_t*)(ws + HB_OFF);
    ushort_t* WFT  = (ushort_t*)(ws + WFT_OFF);
    ushort_t* BAG  = (ushort_t*)(ws + BAG_OFF);
    float* EMBW    = (float*)(ws + EMBW_OFF);
    float* PS      = (float*)(ws + PS_OFF);
    float* S       = (float*)(ws + S_OFF);
    float* STAT    = (float*)(ws + STAT_OFF);
    float* PST     = (float*)(ws + PST_OFF);
    float* CPART   = (float*)(ws + CP_OFF);
    float* CFEAT   = (float*)(ws + CF_OFF);
    float* CFEAT2  = (float*)(ws + CF2_OFF);
    float* S2      = (float*)(ws + S2_OFF);
    float* out     = (float*)d_out;

    conv_h_kernel<<<16384, 256, 0, stream>>>(h, HB);
    prep_wft_kernel<<<1024, 256, 0, stream>>>(Wf, WFT);
    prep_bag_kernel<<<512, 256, 0, stream>>>(Wa, Wb, BAG);
    prep_embw_kernel<<<20, 256, 0, stream>>>(emb, Wf, bf, EMBW);

    gemm_x_mfma<<<dim3(4, 256), 512, 0, stream>>>(HB, cid, WFT, EMBW, XB);
    gemm_ag_mfma<<<dim3(4, 256), 512, 0, stream>>>(XB, BAG, ba, bb, Wc, PS);

    s_combine_kernel<<<256, 256, 0, stream>>>(PS, bc, S);
    stats1_kernel<<<640, 256, 0, stream>>>(S, cid, PST);
    stats2_kernel<<<1, 128, 0, stream>>>(PST, STAT);
    cpart_kernel<<<512, 256, 0, stream>>>(XB, cid, S, STAT, CPART);
    creduce_kernel<<<160, 256, 0, stream>>>(CPART, CFEAT);
    intra_fc_kernel<<<B_ * C_, 256, 0, stream>>>(CFEAT, Wfc, bfc, CFEAT2);
    inter_score_kernel<<<B_ * C_, 256, 0, stream>>>(CFEAT2, Wa2, ba2, Wb2, bb2, Wc2, bc2, S2);
    final_kernel<<<B_, 256, 0, stream>>>(CFEAT2, S2, Wfc2, bfc2, Wcls, bcls, out);
}

// Round 5
// 243.211 us; speedup vs baseline: 3.7576x; 1.1086x over previous
//
#include <hip/hip_runtime.h>
#include <math.h>

#define B_    8
#define N_    8192
#define M_    65536        // B_*N_
#define I_    512
#define E_    8
#define D_    256
#define C_    10
#define NCLS_ 2

typedef unsigned short ushort_t;
typedef ushort_t ushortx8 __attribute__((ext_vector_type(8)));
typedef __bf16   bf16x8  __attribute__((ext_vector_type(8)));
typedef float    f32x4   __attribute__((ext_vector_type(4)));

// ---------------- workspace layout (byte offsets) ----------------
static const size_t XB_OFF   = 0;                         // bf16 x [M_,512] = 64 MB
static const size_t PS_OFF   = 67108864;                  // 8*M_*4 = 2 MB
static const size_t S_OFF    = PS_OFF + 2097152;          // M_*4
static const size_t STAT_OFF = S_OFF + 262144;            // 1024 (160 f32 used)
static const size_t PST_OFF  = STAT_OFF + 1024;           // 1280*4 = 5120
static const size_t CP_OFF   = PST_OFF + 5120;            // 512*10*512*4 = 10 MB
static const size_t CF_OFF   = CP_OFF + 10485760;         // 80*512*4
static const size_t CF2_OFF  = CF_OFF + 163840;
static const size_t S2_OFF   = CF2_OFF + 163840;          // 512 B
static const size_t WFT_OFF  = S2_OFF + 512;              // bf16 [512][512]
static const size_t BAG_OFF  = WFT_OFF + 524288;          // bf16 [512][512]
static const size_t EMBW_OFF = BAG_OFF + 524288;          // f32 [10][512]
// total ~81.4 MB (R2-R4 proved >=135 MB available)

__device__ __forceinline__ float sigf(float v) { return 1.0f / (1.0f + __expf(-v)); }

__device__ __forceinline__ ushort_t f2bf(float f) {
    union { float f; unsigned u; } v; v.f = f;
    unsigned r = v.u + 0x7FFF + ((v.u >> 16) & 1);   // RNE (finite data)
    return (ushort_t)(r >> 16);
}
__device__ __forceinline__ float bf2f(ushort_t u) {
    union { unsigned u; float f; } v; v.u = ((unsigned)u) << 16; return v.f;
}

// async global->LDS, 16B per lane; LDS dest is wave-uniform base + lane*16
__device__ __forceinline__ void gl_lds16(const ushort_t* g, ushort_t* l) {
    __builtin_amdgcn_global_load_lds(
        (const __attribute__((address_space(1))) void*)g,
        (__attribute__((address_space(3))) void*)l, 16, 0, 0);
}

// =====================================================================
// P: fused prep. blocks [0,1024): WfT; [1024,1536): BagT; [1536,1556): embW
// =====================================================================
__global__ __launch_bounds__(256) void prep_kernel(
    const float* __restrict__ Wf, const float* __restrict__ Wa,
    const float* __restrict__ Wb, const float* __restrict__ emb,
    const float* __restrict__ bfv,
    ushort_t* __restrict__ wft, ushort_t* __restrict__ bag,
    float* __restrict__ embW)
{
    const int bid = blockIdx.x;
    const int t = threadIdx.x;
    if (bid < 1024) {
        int idx = bid * 256 + t;                 // (k, n)
        int k = idx >> 9, n = idx & 511;
        wft[(size_t)n * 512 + k] = f2bf(Wf[(size_t)k * 512 + n]);
    } else if (bid < 1536) {
        int idx = (bid - 1024) * 256 + t;        // (k, d)
        int k = idx >> 8, d = idx & 255;
        float a = Wa[(size_t)k * 256 + d];
        float g = Wb[(size_t)k * 256 + d];
        int blk = d >> 5, w = d & 31;
        bag[(size_t)(blk * 64 + w) * 512 + k]      = f2bf(a);
        bag[(size_t)(blk * 64 + 32 + w) * 512 + k] = f2bf(g);
    } else {
        int idx = (bid - 1536) * 256 + t;        // < 5120
        int c = idx >> 9, n = idx & 511;
        float s = bfv[n];
#pragma unroll
        for (int e = 0; e < 8; ++e) s += emb[c * 8 + e] * Wf[(size_t)(512 + e) * 512 + n];
        embW[(size_t)c * 512 + n] = s;
    }
}

// =====================================================================
// K1: x = relu(h@Wf[:512] + embW[cid]) -> bf16.  Fused f32->bf16 convert.
// BM=256 x BN=128, BK=32, 512 thr = 8 waves (4M x 2N), wave tile 64x64.
// A: f32 global -> reg -> cvt -> swizzled ds_write (reg staging).
// B: global_load_lds 16B, linear dest + pre-swizzled source.
// Double-buffered, one barrier per K-step (drains vmcnt + lgkm).
// =====================================================================
__global__ __launch_bounds__(512) void gemm_x_mfma(
    const float* __restrict__ hf, const int* __restrict__ cid,
    const ushort_t* __restrict__ wft, const float* __restrict__ embW,
    ushort_t* __restrict__ xb)
{
    __shared__ ushort_t As[2][256 * 32];   // 32 KB
    __shared__ ushort_t Bs[2][128 * 32];   // 16 KB

    const int t = threadIdx.x;
    // XCD-aware bijective swizzle (nwg = 1024 = 8*128)
    const int lin = blockIdx.y * 4 + blockIdx.x;
    const int swz = (lin & 7) * 128 + (lin >> 3);
    const int n0 = (swz & 3) * 128;
    const int m0 = (swz >> 2) * 256;

    const int wid = t >> 6;                 // 0..7
    const int wr = wid >> 1, wc = wid & 1;  // 4M x 2N wave grid
    const int l = t & 63, lr = l & 15, lg = l >> 4;

    // ---- B staging (gload_lds): wave wid stages B rows [wid*16, wid*16+16)
    const int srow = l >> 2;
    const int gch  = ((l & 3) ^ ((l >> 3) & 3)) * 8;
    const size_t gB0 = (size_t)(n0 + wid * 16 + srow) * 512 + gch;
    ushort_t* lB = &Bs[0][wid * 512];

    // ---- A staging (reg): thread handles row Ar, 16 consecutive f32
    const int Ar  = t >> 1;                  // 0..255
    const int Af  = (t & 1) * 16;            // f32 offset within 32-k window
    const int Ac0 = (t & 1) * 2;             // first 16B-chunk index
    const int Asw = (Ar >> 1) & 3;           // swizzle key
    const int dst0 = Ar * 64 + ((Ac0 ^ Asw) << 4);
    const int dst1 = Ar * 64 + (((Ac0 + 1) ^ Asw) << 4);
    const float* gA = hf + (size_t)(m0 + Ar) * 512 + Af;

    f32x4 acc[4][4] = {};
    float4 a0v, a1v, a2v, a3v;

#define LOADA_X(kt) do { \
    const float4* p4 = (const float4*)(gA + (size_t)(kt) * 32); \
    a0v = p4[0]; a1v = p4[1]; a2v = p4[2]; a3v = p4[3]; \
} while (0)
#define WRITEA_X(buf) do { \
    char* b8 = (char*)As + (buf) * 16384; \
    bf16x8 w0, w1; \
    w0[0]=(__bf16)a0v.x; w0[1]=(__bf16)a0v.y; w0[2]=(__bf16)a0v.z; w0[3]=(__bf16)a0v.w; \
    w0[4]=(__bf16)a1v.x; w0[5]=(__bf16)a1v.y; w0[6]=(__bf16)a1v.z; w0[7]=(__bf16)a1v.w; \
    w1[0]=(__bf16)a2v.x; w1[1]=(__bf16)a2v.y; w1[2]=(__bf16)a2v.z; w1[3]=(__bf16)a2v.w; \
    w1[4]=(__bf16)a3v.x; w1[5]=(__bf16)a3v.y; w1[6]=(__bf16)a3v.z; w1[7]=(__bf16)a3v.w; \
    *(bf16x8*)(b8 + dst0) = w0; \
    *(bf16x8*)(b8 + dst1) = w1; \
} while (0)
#define STAGEB_X(buf, kt) \
    gl_lds16(wft + gB0 + (size_t)(kt) * 32, lB + (buf) * 4096)

    LOADA_X(0);
    STAGEB_X(0, 0);
    WRITEA_X(0);
    __syncthreads();
    int cur = 0;
    for (int kt = 0; kt < 16; ++kt) {
        if (kt < 15) { LOADA_X(kt + 1); STAGEB_X(cur ^ 1, kt + 1); }
        const char* Ab = (const char*)As + cur * 16384;
        const char* Bb = (const char*)Bs + cur * 8192;
        bf16x8 af[4], bg[4];
#pragma unroll
        for (int mi = 0; mi < 4; ++mi) {
            int R = wr * 64 + mi * 16 + lr;
            af[mi] = *(const bf16x8*)(Ab + R * 64 + ((lg ^ ((R >> 1) & 3)) << 4));
        }
#pragma unroll
        for (int ni = 0; ni < 4; ++ni) {
            int Cc = wc * 64 + ni * 16 + lr;
            bg[ni] = *(const bf16x8*)(Bb + Cc * 64 + ((lg ^ ((Cc >> 1) & 3)) << 4));
        }
#pragma unroll
        for (int mi = 0; mi < 4; ++mi)
#pragma unroll
            for (int ni = 0; ni < 4; ++ni)
                acc[mi][ni] = __builtin_amdgcn_mfma_f32_16x16x32_bf16(af[mi], bg[ni], acc[mi][ni], 0, 0, 0);
        if (kt < 15) WRITEA_X(cur ^ 1);
        __syncthreads();   // drains vmcnt(0) (B glds + A f32) and lgkm (A writes)
        cur ^= 1;
    }

    // epilogue: + embW[cid[row]][col], relu, bf16 store
#pragma unroll
    for (int mi = 0; mi < 4; ++mi) {
#pragma unroll
        for (int r = 0; r < 4; ++r) {
            int row = m0 + wr * 64 + mi * 16 + lg * 4 + r;
            const float* ew = embW + (size_t)cid[row] * 512;
#pragma unroll
            for (int ni = 0; ni < 4; ++ni) {
                int col = n0 + wc * 64 + ni * 16 + lr;
                float v = acc[mi][ni][r] + ew[col];
                xb[(size_t)row * 512 + col] = f2bf(fmaxf(v, 0.0f));
            }
        }
    }
}

// =====================================================================
// K2: gated attention partial scores (unchanged from R4, verified).
// =====================================================================
__global__ __launch_bounds__(512) void gemm_ag_mfma(
    const ushort_t* __restrict__ xb, const ushort_t* __restrict__ bag,
    const float* __restrict__ bav, const float* __restrict__ bbv,
    const float* __restrict__ Wc, float* __restrict__ ps)
{
    __shared__ ushort_t As[2][256 * 32];
    __shared__ ushort_t Bs[2][128 * 32];

    const int t = threadIdx.x;
    const int lin = blockIdx.y * 4 + blockIdx.x;
    const int swz = (lin & 7) * 128 + (lin >> 3);
    const int bxn = swz & 3;
    const int n0 = bxn * 128;
    const int m0 = (swz >> 2) * 256;

    const int wid = t >> 6;
    const int wr = wid >> 1, wc = wid & 1;
    const int l = t & 63, lr = l & 15, lg = l >> 4;

    const int srow = l >> 2;
    const int gch  = ((l & 3) ^ ((l >> 3) & 3)) * 8;

    const size_t gA0 = (size_t)(m0 + wid * 32 + srow) * 512 + gch;
    const size_t gA1 = gA0 + 16 * 512;
    const size_t gB0 = (size_t)(n0 + wid * 16 + srow) * 512 + gch;
    ushort_t* lA = &As[0][wid * 1024];
    ushort_t* lB = &Bs[0][wid * 512];

    f32x4 acc[4][4] = {};

#define STAGE_AG(buf, kt) do { \
    size_t ko = (size_t)(kt) * 32; \
    gl_lds16(xb + gA0 + ko,  lA + (buf) * 8192); \
    gl_lds16(xb + gA1 + ko,  lA + (buf) * 8192 + 512); \
    gl_lds16(bag + gB0 + ko, lB + (buf) * 4096); \
} while (0)

    STAGE_AG(0, 0);
    __syncthreads();
    int cur = 0;
    for (int kt = 0; kt < 16; ++kt) {
        if (kt < 15) STAGE_AG(cur ^ 1, kt + 1);
        const char* Ab = (const char*)&As[cur][0];
        const char* Bb = (const char*)&Bs[cur][0];
        bf16x8 af[4], bg[4];
#pragma unroll
        for (int mi = 0; mi < 4; ++mi) {
            int R = wr * 64 + mi * 16 + lr;
            af[mi] = *(const bf16x8*)(Ab + R * 64 + ((lg ^ ((R >> 1) & 3)) << 4));
        }
#pragma unroll
        for (int ni = 0; ni < 4; ++ni) {
            int Cc = wc * 64 + ni * 16 + lr;
            bg[ni] = *(const bf16x8*)(Bb + Cc * 64 + ((lg ^ ((Cc >> 1) & 3)) << 4));
        }
#pragma unroll
        for (int mi = 0; mi < 4; ++mi)
#pragma unroll
            for (int ni = 0; ni < 4; ++ni)
                acc[mi][ni] = __builtin_amdgcn_mfma_f32_16x16x32_bf16(af[mi], bg[ni], acc[mi][ni], 0, 0, 0);
        __syncthreads();
        cur ^= 1;
    }

    const int blk = bxn * 2 + wc;                 // 0..7
    const int d0 = blk * 32 + lr, d1 = d0 + 16;
    const float ba0 = bav[d0], ba1 = bav[d1];
    const float bb0 = bbv[d0], bb1 = bbv[d1];
    const float w0 = Wc[d0],  w1 = Wc[d1];

#pragma unroll
    for (int mi = 0; mi < 4; ++mi) {
#pragma unroll
        for (int r = 0; r < 4; ++r) {
            float p = tanhf(acc[mi][0][r] + ba0) * sigf(acc[mi][2][r] + bb0) * w0
                    + tanhf(acc[mi][1][r] + ba1) * sigf(acc[mi][3][r] + bb1) * w1;
            p += __shfl_xor(p, 1); p += __shfl_xor(p, 2);
            p += __shfl_xor(p, 4); p += __shfl_xor(p, 8);
            if (lr == 0)
                ps[(size_t)blk * M_ + m0 + wr * 64 + mi * 16 + lg * 4 + r] = p;
        }
    }
}

// =====================================================================
// K3: fused s-combine + per-slice segmented stats.  64 blocks = (b, slice
// of 1024 rows); each thread holds 4 rows in regs; max then sum-exp passes
// without re-reading; per-cluster shuffle+LDS reduce.
// =====================================================================
__global__ __launch_bounds__(256) void sstats_kernel(
    const float* __restrict__ ps, const float* __restrict__ bc,
    const int* __restrict__ cid, float* __restrict__ S,
    float* __restrict__ pst)
{
    __shared__ float redm[4][C_];
    __shared__ float smx[C_];
    __shared__ float reds[4][C_];

    const int b  = blockIdx.x >> 3;
    const int sl = blockIdx.x & 7;
    const int bs = blockIdx.x;
    const int t  = threadIdx.x;
    const int l  = t & 63, wv = t >> 6;
    const int base = b * N_ + sl * 1024;

    float sv[4]; int cv[4];
#pragma unroll
    for (int i = 0; i < 4; ++i) {
        int m = base + i * 256 + t;
        float v = bc[0];
#pragma unroll
        for (int k = 0; k < 8; ++k) v += ps[(size_t)k * M_ + m];
        S[m] = v; sv[i] = v; cv[i] = cid[m];
    }

    float mx[C_];
#pragma unroll
    for (int c = 0; c < C_; ++c) mx[c] = -3.0e38f;
#pragma unroll
    for (int i = 0; i < 4; ++i)
#pragma unroll
        for (int c = 0; c < C_; ++c)
            mx[c] = fmaxf(mx[c], (cv[i] == c) ? sv[i] : -3.0e38f);
#pragma unroll
    for (int c = 0; c < C_; ++c) {
        float v = mx[c];
        v = fmaxf(v, __shfl_xor(v, 32)); v = fmaxf(v, __shfl_xor(v, 16));
        v = fmaxf(v, __shfl_xor(v, 8));  v = fmaxf(v, __shfl_xor(v, 4));
        v = fmaxf(v, __shfl_xor(v, 2));  v = fmaxf(v, __shfl_xor(v, 1));
        if (l == 0) redm[wv][c] = v;
    }
    __syncthreads();
    if (t < C_)
        smx[t] = fmaxf(fmaxf(redm[0][t], redm[1][t]), fmaxf(redm[2][t], redm[3][t]));
    __syncthreads();

    float sm[C_];
#pragma unroll
    for (int c = 0; c < C_; ++c) sm[c] = 0.f;
#pragma unroll
    for (int i = 0; i < 4; ++i) {
        float e = expf(sv[i] - smx[cv[i]]);
#pragma unroll
        for (int c = 0; c < C_; ++c) sm[c] += (cv[i] == c) ? e : 0.f;
    }
#pragma unroll
    for (int c = 0; c < C_; ++c) {
        float v = sm[c];
        v += __shfl_xor(v, 32); v += __shfl_xor(v, 16); v += __shfl_xor(v, 8);
        v += __shfl_xor(v, 4);  v += __shfl_xor(v, 2);  v += __shfl_xor(v, 1);
        if (l == 0) reds[wv][c] = v;
    }
    __syncthreads();
    if (t < C_) {
        pst[bs * C_ + t]       = smx[t];
        pst[640 + bs * C_ + t] = reds[0][t] + reds[1][t] + reds[2][t] + reds[3][t];
    }
}

// K4: combine 8 slice partials per (b,c) -> stat (max[80], 1/sumexp[80])
__global__ void stats2_kernel(const float* __restrict__ pst, float* __restrict__ stat)
{
    int t = threadIdx.x;
    if (t < 80) {
        int b = t / C_, c = t % C_;
        float mxv = -3.0e38f;
#pragma unroll
        for (int sl = 0; sl < 8; ++sl)
            mxv = fmaxf(mxv, pst[(b * 8 + sl) * C_ + c]);
        float sum = 0.f;
#pragma unroll
        for (int sl = 0; sl < 8; ++sl)
            sum += pst[640 + (b * 8 + sl) * C_ + c] * expf(pst[(b * 8 + sl) * C_ + c] - mxv);
        stat[t]      = mxv;
        stat[80 + t] = 1.0f / sum;
    }
}

// K5: segmented weighted sums; per-row weights precomputed in LDS once.
__global__ __launch_bounds__(256) void cpart_kernel(
    const ushort_t* __restrict__ xb, const int* __restrict__ cid,
    const float* __restrict__ s, const float* __restrict__ stat,
    float* __restrict__ cpart)
{
    __shared__ float wrow[128];
    __shared__ int   crow[128];
    const int b     = blockIdx.x >> 6;
    const int chunk = blockIdx.x & 63;
    const int t     = threadIdx.x;
    const int base  = b * N_ + chunk * 128;

    if (t < 128) {
        int m = base + t;
        int c = cid[m];
        crow[t] = c;
        wrow[t] = expf(s[m] - stat[b * C_ + c]) * stat[80 + b * C_ + c];
    }
    __syncthreads();

    float2 acc[C_];
#pragma unroll
    for (int c = 0; c < C_; ++c) { acc[c].x = 0.f; acc[c].y = 0.f; }

    for (int r = 0; r < 128; ++r) {
        int c = crow[r];
        float wv = wrow[r];
        unsigned xv = *(const unsigned*)(xb + (size_t)(base + r) * 512 + t * 2);
        float x0 = bf2f((ushort_t)(xv & 0xffff));
        float x1 = bf2f((ushort_t)(xv >> 16));
#pragma unroll
        for (int cc = 0; cc < C_; ++cc) {
            float w = (cc == c) ? wv : 0.0f;
            acc[cc].x += w * x0;
            acc[cc].y += w * x1;
        }
    }
#pragma unroll
    for (int cc = 0; cc < C_; ++cc)
        *(float2*)(&cpart[(((size_t)blockIdx.x) * C_ + cc) * 512 + t * 2]) = acc[cc];
}

// K6a: reduce 64 chunks -> cfeat[b,c,i]
__global__ void creduce_kernel(const float* __restrict__ cpart, float* __restrict__ cfeat)
{
    int o = blockIdx.x * 256 + threadIdx.x;   // < 80*512
    int i = o & 511;
    int bc = o >> 9;
    int b = bc / C_, c = bc % C_;
    float sum = 0.f;
    for (int ch = 0; ch < 64; ++ch)
        sum += cpart[(((size_t)(b * 64 + ch)) * C_ + c) * 512 + i];
    cfeat[o] = sum;
}

// K6b: cfeat2 = relu(cfeat @ Wfc + bfc) AND inter-cluster score s2[bc]
// (block bc only needs its own cfeat2 row -> zero-cost fusion)
__global__ __launch_bounds__(256) void intra_inter_kernel(
    const float* __restrict__ cfeat, const float* __restrict__ Wfc,
    const float* __restrict__ bfc,
    const float* __restrict__ Wa2, const float* __restrict__ ba2,
    const float* __restrict__ Wb2, const float* __restrict__ bb2,
    const float* __restrict__ Wc2, const float* __restrict__ bc2,
    float* __restrict__ cfeat2, float* __restrict__ s2)
{
    __shared__ float row[512];
    __shared__ float row2[512];
    __shared__ float red[256];
    const int bc = blockIdx.x;
    const int t  = threadIdx.x;
    row[t] = cfeat[bc * 512 + t]; row[t + 256] = cfeat[bc * 512 + 256 + t];
    __syncthreads();
    float a0 = 0.f, a1 = 0.f;
    for (int i = 0; i < 512; ++i) {
        float rv = row[i];
        a0 += rv * Wfc[(size_t)i * 512 + t];
        a1 += rv * Wfc[(size_t)i * 512 + 256 + t];
    }
    a0 = fmaxf(a0 + bfc[t], 0.f);
    a1 = fmaxf(a1 + bfc[256 + t], 0.f);
    cfeat2[bc * 512 + t]       = a0;
    cfeat2[bc * 512 + 256 + t] = a1;
    row2[t] = a0; row2[t + 256] = a1;
    __syncthreads();

    float pa = 0.f, pg = 0.f;
    for (int f = 0; f < 512; ++f) {
        float rv = row2[f];
        pa += rv * Wa2[(size_t)f * 256 + t];
        pg += rv * Wb2[(size_t)f * 256 + t];
    }
    float v = tanhf(pa + ba2[t]) * sigf(pg + bb2[t]) * Wc2[t];
    red[t] = v; __syncthreads();
    for (int off = 128; off > 0; off >>= 1) {
        if (t < off) red[t] += red[t + off];
        __syncthreads();
    }
    if (t == 0) s2[bc] = red[0] + bc2[0];
}

// K7: softmax over C, slide pooling, final fc + classifier
__global__ __launch_bounds__(256) void final_kernel(
    const float* __restrict__ cfeat2, const float* __restrict__ s2,
    const float* __restrict__ Wfc2, const float* __restrict__ bfc2,
    const float* __restrict__ Wcls, const float* __restrict__ bcls,
    float* __restrict__ out)
{
    __shared__ float A2[C_];
    __shared__ float slide[512];
    __shared__ float slide2[256];
    const int b = blockIdx.x;
    const int t = threadIdx.x;

    if (t < C_) A2[t] = s2[b * C_ + t];
    __syncthreads();
    float mx = -3.0e38f;
    for (int c = 0; c < C_; ++c) mx = fmaxf(mx, A2[c]);
    float sum = 0.f;
    for (int c = 0; c < C_; ++c) sum += expf(A2[c] - mx);
    __syncthreads();
    if (t < C_) A2[t] = expf(A2[t] - mx) / sum;
    __syncthreads();

    float s0 = 0.f, s1 = 0.f;
    for (int c = 0; c < C_; ++c) {
        float a = A2[c];
        s0 += a * cfeat2[(b * C_ + c) * 512 + t];
        s1 += a * cfeat2[(b * C_ + c) * 512 + 256 + t];
    }
    slide[t] = s0; slide[t + 256] = s1;
    __syncthreads();

    float acc = 0.f;
    for (int f = 0; f < 512; ++f) acc += slide[f] * Wfc2[(size_t)f * 256 + t];
    slide2[t] = fmaxf(acc + bfc2[t], 0.f);
    __syncthreads();

    if (t < NCLS_) {
        float lg = bcls[t];
        for (int o = 0; o < 256; ++o) lg += slide2[o] * Wcls[o * 2 + t];
        out[b * 2 + t] = lg;
    }
}

extern "C" void kernel_launch(void* const* d_in, const int* in_sizes, int n_in,
                              void* d_out, int out_size, void* d_ws, size_t ws_size,
                              hipStream_t stream)
{
    (void)in_sizes; (void)n_in; (void)out_size; (void)ws_size;
    const float* h    = (const float*)d_in[0];
    const int*   cid  = (const int*)  d_in[1];
    const float* emb  = (const float*)d_in[2];
    const float* Wf   = (const float*)d_in[3];
    const float* bf   = (const float*)d_in[4];
    const float* Wa   = (const float*)d_in[5];
    const float* ba   = (const float*)d_in[6];
    const float* Wb   = (const float*)d_in[7];
    const float* bb   = (const float*)d_in[8];
    const float* Wc   = (const float*)d_in[9];
    const float* bc   = (const float*)d_in[10];
    const float* Wfc  = (const float*)d_in[11];
    const float* bfc  = (const float*)d_in[12];
    const float* Wa2  = (const float*)d_in[13];
    const float* ba2  = (const float*)d_in[14];
    const float* Wb2  = (const float*)d_in[15];
    const float* bb2  = (const float*)d_in[16];
    const float* Wc2  = (const float*)d_in[17];
    const float* bc2  = (const float*)d_in[18];
    const float* Wfc2 = (const float*)d_in[19];
    const float* bfc2 = (const float*)d_in[20];
    const float* Wcls = (const float*)d_in[21];
    const float* bcls = (const float*)d_in[22];

    char* ws = (char*)d_ws;
    ushort_t* XB   = (ushort_t*)(ws + XB_OFF);
    float* PS      = (float*)(ws + PS_OFF);
    float* S       = (float*)(ws + S_OFF);
    float* STAT    = (float*)(ws + STAT_OFF);
    float* PST     = (float*)(ws + PST_OFF);
    float* CPART   = (float*)(ws + CP_OFF);
    float* CFEAT   = (float*)(ws + CF_OFF);
    float* CFEAT2  = (float*)(ws + CF2_OFF);
    float* S2      = (float*)(ws + S2_OFF);
    ushort_t* WFT  = (ushort_t*)(ws + WFT_OFF);
    ushort_t* BAG  = (ushort_t*)(ws + BAG_OFF);
    float* EMBW    = (float*)(ws + EMBW_OFF);
    float* out     = (float*)d_out;

    prep_kernel<<<1556, 256, 0, stream>>>(Wf, Wa, Wb, emb, bf, WFT, BAG, EMBW);

    gemm_x_mfma<<<dim3(4, 256), 512, 0, stream>>>(h, cid, WFT, EMBW, XB);
    gemm_ag_mfma<<<dim3(4, 256), 512, 0, stream>>>(XB, BAG, ba, bb, Wc, PS);

    sstats_kernel<<<64, 256, 0, stream>>>(PS, bc, cid, S, PST);
    stats2_kernel<<<1, 128, 0, stream>>>(PST, STAT);
    cpart_kernel<<<512, 256, 0, stream>>>(XB, cid, S, STAT, CPART);
    creduce_kernel<<<160, 256, 0, stream>>>(CPART, CFEAT);
    intra_inter_kernel<<<B_ * C_, 256, 0, stream>>>(CFEAT, Wfc, bfc,
                                                    Wa2, ba2, Wb2, bb2, Wc2, bc2,
                                                    CFEAT2, S2);
    final_kernel<<<B_, 256, 0, stream>>>(CFEAT2, S2, Wfc2, bfc2, Wcls, bcls, out);
}

// Round 6
// 223.448 us; speedup vs baseline: 4.0899x; 1.0884x over previous
//
#include <hip/hip_runtime.h>
#include <math.h>

#define B_    8
#define N_    8192
#define M_    65536        // B_*N_
#define I_    512
#define E_    8
#define D_    256
#define C_    10
#define NCLS_ 2

typedef unsigned short ushort_t;
typedef ushort_t ushortx8 __attribute__((ext_vector_type(8)));
typedef __bf16   bf16x8  __attribute__((ext_vector_type(8)));
typedef float    f32x4   __attribute__((ext_vector_type(4)));

// ---------------- workspace layout (byte offsets) ----------------
static const size_t XB_OFF   = 0;                         // bf16 x [M_,512] = 64 MB
static const size_t PS_OFF   = 67108864;                  // 8*M_*4 = 2 MB
static const size_t S_OFF    = PS_OFF + 2097152;          // M_*4
static const size_t STAT_OFF = S_OFF + 262144;            // 1024 (160 f32 used)
static const size_t PST_OFF  = STAT_OFF + 1024;           // 1280*4 = 5120
static const size_t CP_OFF   = PST_OFF + 5120;            // 512*10*512*4 = 10 MB
static const size_t CF_OFF   = CP_OFF + 10485760;         // 80*512*4
static const size_t CF2_OFF  = CF_OFF + 163840;
static const size_t S2_OFF   = CF2_OFF + 163840;          // 512 B
static const size_t WFT_OFF  = S2_OFF + 512;              // bf16 [512][512]
static const size_t BAG_OFF  = WFT_OFF + 524288;          // bf16 [512][512]
static const size_t EMBW_OFF = BAG_OFF + 524288;          // f32 [10][512]

__device__ __forceinline__ float sigf(float v) { return 1.0f / (1.0f + __expf(-v)); }

__device__ __forceinline__ ushort_t f2bf(float f) {
    union { float f; unsigned u; } v; v.f = f;
    unsigned r = v.u + 0x7FFF + ((v.u >> 16) & 1);   // RNE (finite data)
    return (ushort_t)(r >> 16);
}
__device__ __forceinline__ float bf2f(ushort_t u) {
    union { unsigned u; float f; } v; v.u = ((unsigned)u) << 16; return v.f;
}

// async global->LDS, 16B per lane; LDS dest is wave-uniform base + lane*16
__device__ __forceinline__ void gl_lds16(const void* g, void* l) {
    __builtin_amdgcn_global_load_lds(
        (const __attribute__((address_space(1))) void*)g,
        (__attribute__((address_space(3))) void*)l, 16, 0, 0);
}

// =====================================================================
// P: fused prep. blocks [0,1024): WfT; [1024,1536): BagT; [1536,1556): embW
// =====================================================================
__global__ __launch_bounds__(256) void prep_kernel(
    const float* __restrict__ Wf, const float* __restrict__ Wa,
    const float* __restrict__ Wb, const float* __restrict__ emb,
    const float* __restrict__ bfv,
    ushort_t* __restrict__ wft, ushort_t* __restrict__ bag,
    float* __restrict__ embW)
{
    const int bid = blockIdx.x;
    const int t = threadIdx.x;
    if (bid < 1024) {
        int idx = bid * 256 + t;                 // (k, n)
        int k = idx >> 9, n = idx & 511;
        wft[(size_t)n * 512 + k] = f2bf(Wf[(size_t)k * 512 + n]);
    } else if (bid < 1536) {
        int idx = (bid - 1024) * 256 + t;        // (k, d)
        int k = idx >> 8, d = idx & 255;
        float a = Wa[(size_t)k * 256 + d];
        float g = Wb[(size_t)k * 256 + d];
        int blk = d >> 5, w = d & 31;
        bag[(size_t)(blk * 64 + w) * 512 + k]      = f2bf(a);
        bag[(size_t)(blk * 64 + 32 + w) * 512 + k] = f2bf(g);
    } else {
        int idx = (bid - 1536) * 256 + t;        // < 5120
        int c = idx >> 9, n = idx & 511;
        float s = bfv[n];
#pragma unroll
        for (int e = 0; e < 8; ++e) s += emb[c * 8 + e] * Wf[(size_t)(512 + e) * 512 + n];
        embW[(size_t)c * 512 + n] = s;
    }
}

// =====================================================================
// K1: x = relu(h@Wf[:512] + embW[cid]) -> bf16, fused f32 input.
// BM=256 x BN=128, BK=32, 512 thr = 8 waves (4M x 2N), wave tile 64x64.
// A: f32 staged via global_load_lds (async) into swizzled f32 LDS
//    (physical 16B-chunk p of row holds logical chunk p^(row&7), via
//    linear dest + lane-swizzled source); converted to bf16 at
//    fragment-read time (2x ds_read_b128 + cvt casts, 2-way bank = free).
// B: bf16 global_load_lds, linear dest + pre-swizzled source (R4-proven).
// Double-buffered, one barrier per K-step (implicit vmcnt(0) drain).
// =====================================================================
__global__ __launch_bounds__(512) void gemm_x_mfma(
    const float* __restrict__ hf, const int* __restrict__ cid,
    const ushort_t* __restrict__ wft, const float* __restrict__ embW,
    ushort_t* __restrict__ xb)
{
    __shared__ float    Asf[2][256 * 32];   // 64 KB (f32 A tiles)
    __shared__ ushort_t Bs[2][128 * 32];    // 16 KB

    const int t = threadIdx.x;
    // XCD-aware bijective swizzle (nwg = 1024 = 8*128)
    const int lin = blockIdx.y * 4 + blockIdx.x;
    const int swz = (lin & 7) * 128 + (lin >> 3);
    const int n0 = (swz & 3) * 128;
    const int m0 = (swz >> 2) * 256;

    const int wid = t >> 6;                 // 0..7
    const int wr = wid >> 1, wc = wid & 1;  // 4M x 2N wave grid
    const int l = t & 63, lr = l & 15, lg = l >> 4;

    // ---- B staging (gload_lds, bf16): wave wid stages rows [wid*16, wid*16+16)
    const int srow = l >> 2;
    const int gchB = ((l & 3) ^ ((l >> 3) & 3)) * 8;
    const size_t gB0 = (size_t)(n0 + wid * 16 + srow) * 512 + gchB;
    ushort_t* lB = &Bs[0][wid * 512];

    // ---- A staging (gload_lds, f32): wave wid stages rows [wid*32, wid*32+32),
    // 4 issues of 8 rows each; lane covers row wid*32+j*8+(l>>3), chunk l&7.
    const int ArowL = wid * 32 + (l >> 3);
    const int gchA  = ((l & 7) ^ ((l >> 3) & 7)) * 4;          // f32 offset
    const size_t gAf = (size_t)(m0 + ArowL) * 512 + gchA;
    // LDS dest base (bytes) for issue j: wid*4096 + j*1024 (+ lane*16 by HW)

    f32x4 acc[4][4] = {};

#define STAGE_X(buf, kt) do { \
    size_t ko = (size_t)(kt) * 32; \
    char* aB = (char*)&Asf[buf][0] + wid * 4096; \
    gl_lds16(hf + gAf + ko,            aB); \
    gl_lds16(hf + gAf + ko +  8 * 512, aB + 1024); \
    gl_lds16(hf + gAf + ko + 16 * 512, aB + 2048); \
    gl_lds16(hf + gAf + ko + 24 * 512, aB + 3072); \
    gl_lds16(wft + gB0 + ko, lB + (buf) * 4096); \
} while (0)

    STAGE_X(0, 0);
    __syncthreads();
    int cur = 0;
    for (int kt = 0; kt < 16; ++kt) {
        if (kt < 15) STAGE_X(cur ^ 1, kt + 1);
        const float* Aw = &Asf[cur][0];
        const char*  Bb = (const char*)&Bs[cur][0];
        bf16x8 af[4], bg[4];
#pragma unroll
        for (int mi = 0; mi < 4; ++mi) {
            int R = wr * 64 + mi * 16 + lr;
            const float* Arow = Aw + R * 32;
            int s7 = R & 7;
            f32x4 lo = *(const f32x4*)(Arow + (((2 * lg)     ^ s7) << 2));
            f32x4 hi = *(const f32x4*)(Arow + (((2 * lg + 1) ^ s7) << 2));
            bf16x8 a;
            a[0] = (__bf16)lo[0]; a[1] = (__bf16)lo[1];
            a[2] = (__bf16)lo[2]; a[3] = (__bf16)lo[3];
            a[4] = (__bf16)hi[0]; a[5] = (__bf16)hi[1];
            a[6] = (__bf16)hi[2]; a[7] = (__bf16)hi[3];
            af[mi] = a;
        }
#pragma unroll
        for (int ni = 0; ni < 4; ++ni) {
            int Cc = wc * 64 + ni * 16 + lr;
            bg[ni] = *(const bf16x8*)(Bb + Cc * 64 + ((lg ^ ((Cc >> 1) & 3)) << 4));
        }
#pragma unroll
        for (int mi = 0; mi < 4; ++mi)
#pragma unroll
            for (int ni = 0; ni < 4; ++ni)
                acc[mi][ni] = __builtin_amdgcn_mfma_f32_16x16x32_bf16(af[mi], bg[ni], acc[mi][ni], 0, 0, 0);
        __syncthreads();   // implicit vmcnt(0): next tile staged & visible
        cur ^= 1;
    }

    // epilogue: + embW[cid[row]][col], relu, bf16 store
#pragma unroll
    for (int mi = 0; mi < 4; ++mi) {
#pragma unroll
        for (int r = 0; r < 4; ++r) {
            int row = m0 + wr * 64 + mi * 16 + lg * 4 + r;
            const float* ew = embW + (size_t)cid[row] * 512;
#pragma unroll
            for (int ni = 0; ni < 4; ++ni) {
                int col = n0 + wc * 64 + ni * 16 + lr;
                float v = acc[mi][ni][r] + ew[col];
                xb[(size_t)row * 512 + col] = f2bf(fmaxf(v, 0.0f));
            }
        }
    }
}

// =====================================================================
// K2: gated attention partial scores (unchanged, verified).
// =====================================================================
__global__ __launch_bounds__(512) void gemm_ag_mfma(
    const ushort_t* __restrict__ xb, const ushort_t* __restrict__ bag,
    const float* __restrict__ bav, const float* __restrict__ bbv,
    const float* __restrict__ Wc, float* __restrict__ ps)
{
    __shared__ ushort_t As[2][256 * 32];
    __shared__ ushort_t Bs[2][128 * 32];

    const int t = threadIdx.x;
    const int lin = blockIdx.y * 4 + blockIdx.x;
    const int swz = (lin & 7) * 128 + (lin >> 3);
    const int bxn = swz & 3;
    const int n0 = bxn * 128;
    const int m0 = (swz >> 2) * 256;

    const int wid = t >> 6;
    const int wr = wid >> 1, wc = wid & 1;
    const int l = t & 63, lr = l & 15, lg = l >> 4;

    const int srow = l >> 2;
    const int gch  = ((l & 3) ^ ((l >> 3) & 3)) * 8;

    const size_t gA0 = (size_t)(m0 + wid * 32 + srow) * 512 + gch;
    const size_t gA1 = gA0 + 16 * 512;
    const size_t gB0 = (size_t)(n0 + wid * 16 + srow) * 512 + gch;
    ushort_t* lA = &As[0][wid * 1024];
    ushort_t* lB = &Bs[0][wid * 512];

    f32x4 acc[4][4] = {};

#define STAGE_AG(buf, kt) do { \
    size_t ko = (size_t)(kt) * 32; \
    gl_lds16(xb + gA0 + ko,  lA + (buf) * 8192); \
    gl_lds16(xb + gA1 + ko,  lA + (buf) * 8192 + 512); \
    gl_lds16(bag + gB0 + ko, lB + (buf) * 4096); \
} while (0)

    STAGE_AG(0, 0);
    __syncthreads();
    int cur = 0;
    for (int kt = 0; kt < 16; ++kt) {
        if (kt < 15) STAGE_AG(cur ^ 1, kt + 1);
        const char* Ab = (const char*)&As[cur][0];
        const char* Bb = (const char*)&Bs[cur][0];
        bf16x8 af[4], bg[4];
#pragma unroll
        for (int mi = 0; mi < 4; ++mi) {
            int R = wr * 64 + mi * 16 + lr;
            af[mi] = *(const bf16x8*)(Ab + R * 64 + ((lg ^ ((R >> 1) & 3)) << 4));
        }
#pragma unroll
        for (int ni = 0; ni < 4; ++ni) {
            int Cc = wc * 64 + ni * 16 + lr;
            bg[ni] = *(const bf16x8*)(Bb + Cc * 64 + ((lg ^ ((Cc >> 1) & 3)) << 4));
        }
#pragma unroll
        for (int mi = 0; mi < 4; ++mi)
#pragma unroll
            for (int ni = 0; ni < 4; ++ni)
                acc[mi][ni] = __builtin_amdgcn_mfma_f32_16x16x32_bf16(af[mi], bg[ni], acc[mi][ni], 0, 0, 0);
        __syncthreads();
        cur ^= 1;
    }

    const int blk = bxn * 2 + wc;                 // 0..7
    const int d0 = blk * 32 + lr, d1 = d0 + 16;
    const float ba0 = bav[d0], ba1 = bav[d1];
    const float bb0 = bbv[d0], bb1 = bbv[d1];
    const float w0 = Wc[d0],  w1 = Wc[d1];

#pragma unroll
    for (int mi = 0; mi < 4; ++mi) {
#pragma unroll
        for (int r = 0; r < 4; ++r) {
            float p = tanhf(acc[mi][0][r] + ba0) * sigf(acc[mi][2][r] + bb0) * w0
                    + tanhf(acc[mi][1][r] + ba1) * sigf(acc[mi][3][r] + bb1) * w1;
            p += __shfl_xor(p, 1); p += __shfl_xor(p, 2);
            p += __shfl_xor(p, 4); p += __shfl_xor(p, 8);
            if (lr == 0)
                ps[(size_t)blk * M_ + m0 + wr * 64 + mi * 16 + lg * 4 + r] = p;
        }
    }
}

// =====================================================================
// K3: fused s-combine + per-slice segmented stats.
// =====================================================================
__global__ __launch_bounds__(256) void sstats_kernel(
    const float* __restrict__ ps, const float* __restrict__ bc,
    const int* __restrict__ cid, float* __restrict__ S,
    float* __restrict__ pst)
{
    __shared__ float redm[4][C_];
    __shared__ float smx[C_];
    __shared__ float reds[4][C_];

    const int b  = blockIdx.x >> 3;
    const int sl = blockIdx.x & 7;
    const int bs = blockIdx.x;
    const int t  = threadIdx.x;
    const int l  = t & 63, wv = t >> 6;
    const int base = b * N_ + sl * 1024;

    float sv[4]; int cv[4];
#pragma unroll
    for (int i = 0; i < 4; ++i) {
        int m = base + i * 256 + t;
        float v = bc[0];
#pragma unroll
        for (int k = 0; k < 8; ++k) v += ps[(size_t)k * M_ + m];
        S[m] = v; sv[i] = v; cv[i] = cid[m];
    }

    float mx[C_];
#pragma unroll
    for (int c = 0; c < C_; ++c) mx[c] = -3.0e38f;
#pragma unroll
    for (int i = 0; i < 4; ++i)
#pragma unroll
        for (int c = 0; c < C_; ++c)
            mx[c] = fmaxf(mx[c], (cv[i] == c) ? sv[i] : -3.0e38f);
#pragma unroll
    for (int c = 0; c < C_; ++c) {
        float v = mx[c];
        v = fmaxf(v, __shfl_xor(v, 32)); v = fmaxf(v, __shfl_xor(v, 16));
        v = fmaxf(v, __shfl_xor(v, 8));  v = fmaxf(v, __shfl_xor(v, 4));
        v = fmaxf(v, __shfl_xor(v, 2));  v = fmaxf(v, __shfl_xor(v, 1));
        if (l == 0) redm[wv][c] = v;
    }
    __syncthreads();
    if (t < C_)
        smx[t] = fmaxf(fmaxf(redm[0][t], redm[1][t]), fmaxf(redm[2][t], redm[3][t]));
    __syncthreads();

    float sm[C_];
#pragma unroll
    for (int c = 0; c < C_; ++c) sm[c] = 0.f;
#pragma unroll
    for (int i = 0; i < 4; ++i) {
        float e = expf(sv[i] - smx[cv[i]]);
#pragma unroll
        for (int c = 0; c < C_; ++c) sm[c] += (cv[i] == c) ? e : 0.f;
    }
#pragma unroll
    for (int c = 0; c < C_; ++c) {
        float v = sm[c];
        v += __shfl_xor(v, 32); v += __shfl_xor(v, 16); v += __shfl_xor(v, 8);
        v += __shfl_xor(v, 4);  v += __shfl_xor(v, 2);  v += __shfl_xor(v, 1);
        if (l == 0) reds[wv][c] = v;
    }
    __syncthreads();
    if (t < C_) {
        pst[bs * C_ + t]       = smx[t];
        pst[640 + bs * C_ + t] = reds[0][t] + reds[1][t] + reds[2][t] + reds[3][t];
    }
}

// K4: combine 8 slice partials per (b,c) -> stat (max[80], 1/sumexp[80])
__global__ void stats2_kernel(const float* __restrict__ pst, float* __restrict__ stat)
{
    int t = threadIdx.x;
    if (t < 80) {
        int b = t / C_, c = t % C_;
        float mxv = -3.0e38f;
#pragma unroll
        for (int sl = 0; sl < 8; ++sl)
            mxv = fmaxf(mxv, pst[(b * 8 + sl) * C_ + c]);
        float sum = 0.f;
#pragma unroll
        for (int sl = 0; sl < 8; ++sl)
            sum += pst[640 + (b * 8 + sl) * C_ + c] * expf(pst[(b * 8 + sl) * C_ + c] - mxv);
        stat[t]      = mxv;
        stat[80 + t] = 1.0f / sum;
    }
}

// K5: segmented weighted sums; per-row weights precomputed in LDS once.
__global__ __launch_bounds__(256) void cpart_kernel(
    const ushort_t* __restrict__ xb, const int* __restrict__ cid,
    const float* __restrict__ s, const float* __restrict__ stat,
    float* __restrict__ cpart)
{
    __shared__ float wrow[128];
    __shared__ int   crow[128];
    const int b     = blockIdx.x >> 6;
    const int chunk = blockIdx.x & 63;
    const int t     = threadIdx.x;
    const int base  = b * N_ + chunk * 128;

    if (t < 128) {
        int m = base + t;
        int c = cid[m];
        crow[t] = c;
        wrow[t] = expf(s[m] - stat[b * C_ + c]) * stat[80 + b * C_ + c];
    }
    __syncthreads();

    float2 acc[C_];
#pragma unroll
    for (int c = 0; c < C_; ++c) { acc[c].x = 0.f; acc[c].y = 0.f; }

    for (int r = 0; r < 128; ++r) {
        int c = crow[r];
        float wv = wrow[r];
        unsigned xv = *(const unsigned*)(xb + (size_t)(base + r) * 512 + t * 2);
        float x0 = bf2f((ushort_t)(xv & 0xffff));
        float x1 = bf2f((ushort_t)(xv >> 16));
#pragma unroll
        for (int cc = 0; cc < C_; ++cc) {
            float w = (cc == c) ? wv : 0.0f;
            acc[cc].x += w * x0;
            acc[cc].y += w * x1;
        }
    }
#pragma unroll
    for (int cc = 0; cc < C_; ++cc)
        *(float2*)(&cpart[(((size_t)blockIdx.x) * C_ + cc) * 512 + t * 2]) = acc[cc];
}

// K6a: reduce 64 chunks -> cfeat[b,c,i]
__global__ void creduce_kernel(const float* __restrict__ cpart, float* __restrict__ cfeat)
{
    int o = blockIdx.x * 256 + threadIdx.x;   // < 80*512
    int i = o & 511;
    int bc = o >> 9;
    int b = bc / C_, c = bc % C_;
    float sum = 0.f;
    for (int ch = 0; ch < 64; ++ch)
        sum += cpart[(((size_t)(b * 64 + ch)) * C_ + c) * 512 + i];
    cfeat[o] = sum;
}

// K6b: cfeat2 = relu(cfeat @ Wfc + bfc) AND inter-cluster score s2[bc]
__global__ __launch_bounds__(256) void intra_inter_kernel(
    const float* __restrict__ cfeat, const float* __restrict__ Wfc,
    const float* __restrict__ bfc,
    const float* __restrict__ Wa2, const float* __restrict__ ba2,
    const float* __restrict__ Wb2, const float* __restrict__ bb2,
    const float* __restrict__ Wc2, const float* __restrict__ bc2,
    float* __restrict__ cfeat2, float* __restrict__ s2)
{
    __shared__ float row[512];
    __shared__ float row2[512];
    __shared__ float red[256];
    const int bc = blockIdx.x;
    const int t  = threadIdx.x;
    row[t] = cfeat[bc * 512 + t]; row[t + 256] = cfeat[bc * 512 + 256 + t];
    __syncthreads();
    float a0 = 0.f, a1 = 0.f;
    for (int i = 0; i < 512; ++i) {
        float rv = row[i];
        a0 += rv * Wfc[(size_t)i * 512 + t];
        a1 += rv * Wfc[(size_t)i * 512 + 256 + t];
    }
    a0 = fmaxf(a0 + bfc[t], 0.f);
    a1 = fmaxf(a1 + bfc[256 + t], 0.f);
    cfeat2[bc * 512 + t]       = a0;
    cfeat2[bc * 512 + 256 + t] = a1;
    row2[t] = a0; row2[t + 256] = a1;
    __syncthreads();

    float pa = 0.f, pg = 0.f;
    for (int f = 0; f < 512; ++f) {
        float rv = row2[f];
        pa += rv * Wa2[(size_t)f * 256 + t];
        pg += rv * Wb2[(size_t)f * 256 + t];
    }
    float v = tanhf(pa + ba2[t]) * sigf(pg + bb2[t]) * Wc2[t];
    red[t] = v; __syncthreads();
    for (int off = 128; off > 0; off >>= 1) {
        if (t < off) red[t] += red[t + off];
        __syncthreads();
    }
    if (t == 0) s2[bc] = red[0] + bc2[0];
}

// K7: softmax over C, slide pooling, final fc + classifier
__global__ __launch_bounds__(256) void final_kernel(
    const float* __restrict__ cfeat2, const float* __restrict__ s2,
    const float* __restrict__ Wfc2, const float* __restrict__ bfc2,
    const float* __restrict__ Wcls, const float* __restrict__ bcls,
    float* __restrict__ out)
{
    __shared__ float A2[C_];
    __shared__ float slide[512];
    __shared__ float slide2[256];
    const int b = blockIdx.x;
    const int t = threadIdx.x;

    if (t < C_) A2[t] = s2[b * C_ + t];
    __syncthreads();
    float mx = -3.0e38f;
    for (int c = 0; c < C_; ++c) mx = fmaxf(mx, A2[c]);
    float sum = 0.f;
    for (int c = 0; c < C_; ++c) sum += expf(A2[c] - mx);
    __syncthreads();
    if (t < C_) A2[t] = expf(A2[t] - mx) / sum;
    __syncthreads();

    float s0 = 0.f, s1 = 0.f;
    for (int c = 0; c < C_; ++c) {
        float a = A2[c];
        s0 += a * cfeat2[(b * C_ + c) * 512 + t];
        s1 += a * cfeat2[(b * C_ + c) * 512 + 256 + t];
    }
    slide[t] = s0; slide[t + 256] = s1;
    __syncthreads();

    float acc = 0.f;
    for (int f = 0; f < 512; ++f) acc += slide[f] * Wfc2[(size_t)f * 256 + t];
    slide2[t] = fmaxf(acc + bfc2[t], 0.f);
    __syncthreads();

    if (t < NCLS_) {
        float lg = bcls[t];
        for (int o = 0; o < 256; ++o) lg += slide2[o] * Wcls[o * 2 + t];
        out[b * 2 + t] = lg;
    }
}

extern "C" void kernel_launch(void* const* d_in, const int* in_sizes, int n_in,
                              void* d_out, int out_size, void* d_ws, size_t ws_size,
                              hipStream_t stream)
{
    (void)in_sizes; (void)n_in; (void)out_size; (void)ws_size;
    const float* h    = (const float*)d_in[0];
    const int*   cid  = (const int*)  d_in[1];
    const float* emb  = (const float*)d_in[2];
    const float* Wf   = (const float*)d_in[3];
    const float* bf   = (const float*)d_in[4];
    const float* Wa   = (const float*)d_in[5];
    const float* ba   = (const float*)d_in[6];
    const float* Wb   = (const float*)d_in[7];
    const float* bb   = (const float*)d_in[8];
    const float* Wc   = (const float*)d_in[9];
    const float* bc   = (const float*)d_in[10];
    const float* Wfc  = (const float*)d_in[11];
    const float* bfc  = (const float*)d_in[12];
    const float* Wa2  = (const float*)d_in[13];
    const float* ba2  = (const float*)d_in[14];
    const float* Wb2  = (const float*)d_in[15];
    const float* bb2  = (const float*)d_in[16];
    const float* Wc2  = (const float*)d_in[17];
    const float* bc2  = (const float*)d_in[18];
    const float* Wfc2 = (const float*)d_in[19];
    const float* bfc2 = (const float*)d_in[20];
    const float* Wcls = (const float*)d_in[21];
    const float* bcls = (const float*)d_in[22];

    char* ws = (char*)d_ws;
    ushort_t* XB   = (ushort_t*)(ws + XB_OFF);
    float* PS      = (float*)(ws + PS_OFF);
    float* S       = (float*)(ws + S_OFF);
    float* STAT    = (float*)(ws + STAT_OFF);
    float* PST     = (float*)(ws + PST_OFF);
    float* CPART   = (float*)(ws + CP_OFF);
    float* CFEAT   = (float*)(ws + CF_OFF);
    float* CFEAT2  = (float*)(ws + CF2_OFF);
    float* S2      = (float*)(ws + S2_OFF);
    ushort_t* WFT  = (ushort_t*)(ws + WFT_OFF);
    ushort_t* BAG  = (ushort_t*)(ws + BAG_OFF);
    float* EMBW    = (float*)(ws + EMBW_OFF);
    float* out     = (float*)d_out;

    prep_kernel<<<1556, 256, 0, stream>>>(Wf, Wa, Wb, emb, bf, WFT, BAG, EMBW);

    gemm_x_mfma<<<dim3(4, 256), 512, 0, stream>>>(h, cid, WFT, EMBW, XB);
    gemm_ag_mfma<<<dim3(4, 256), 512, 0, stream>>>(XB, BAG, ba, bb, Wc, PS);

    sstats_kernel<<<64, 256, 0, stream>>>(PS, bc, cid, S, PST);
    stats2_kernel<<<1, 128, 0, stream>>>(PST, STAT);
    cpart_kernel<<<512, 256, 0, stream>>>(XB, cid, S, STAT, CPART);
    creduce_kernel<<<160, 256, 0, stream>>>(CPART, CFEAT);
    intra_inter_kernel<<<B_ * C_, 256, 0, stream>>>(CFEAT, Wfc, bfc,
                                                    Wa2, ba2, Wb2, bb2, Wc2, bc2,
                                                    CFEAT2, S2);
    final_kernel<<<B_, 256, 0, stream>>>(CFEAT2, S2, Wfc2, bfc2, Wcls, bcls, out);
}